// Round 7
// baseline (163.222 us; speedup 1.0000x reference)
//
#include <hip/hip_runtime.h>
#include <math.h>

#define TSEQ 1024
#define CD   768
#define HN   12
#define DD   64

// workspace float offsets (~20 MB total)
#define OFF_QH     0          // bf16 12*1024*64 -> 393216 floats each
#define OFF_KH     393216
#define OFF_GH     786432
#define OFF_VHT    1179648    // bf16 d-major [H][D][T]
#define OFF_VH     1572864    // bf16 row-major [H][T][D]
#define OFF_G2     1966080    // 12*1024
#define OFF_YB     1978368    // bf16 1024*768
#define OFF_CONSTS 2371584    // 512
#define OFF_OPART  2372096    // 786432
#define OFF_LS     3158528    // 12288 (must follow OPART for zeroing)
#define OFF_PD     3170816    // 12288
#define OFF_XB     3183104    // bf16 1024*768
#define OFF_WQB    3576320    // bf16 3072*768
#define OFF_WOB    4755968    // bf16 768*768 (end 5050880 floats)
#define NZERO4     199680     // (786432+12288)/4 : Opart+lsp

#define N_XB  786432
#define N_WQB 2359296
#define N_WOB 589824

typedef __bf16 bf16x8 __attribute__((ext_vector_type(8)));
typedef float  f32x4  __attribute__((ext_vector_type(4)));
typedef unsigned short u16x8 __attribute__((ext_vector_type(8)));
typedef unsigned short u16x4 __attribute__((ext_vector_type(4)));

__device__ inline unsigned short f2bf(float f) {
  unsigned int u = __float_as_uint(f);
  return (unsigned short)((u + 0x7fffu + ((u >> 16) & 1u)) >> 16);  // RNE
}
__device__ inline float bf2f(unsigned short u) {
  return __uint_as_float((unsigned)u << 16);
}

// consts per head (stride 24): [0]=lam*dp_scale/6.4, [1]=(1-lam)*logk_scale,
// [2]=clip(beta)/2, [3]=out_scale, [4..11]=1/(4*tau), [12..19]=log2(w+1e-12),
// [20]=ntt (1 if uniform tau & w, else 8). alpha at [288].

__global__ __launch_bounds__(64) void prep_kernel(
    const float* __restrict__ lam_p, const float* __restrict__ log_tau,
    const float* __restrict__ logit_w, const float* __restrict__ beta,
    const float* __restrict__ out_scale, const float* __restrict__ dp_scale,
    const float* __restrict__ logk_scale, const float* __restrict__ dt_logit,
    float* __restrict__ consts) {
  int h = threadIdx.x;
  if (h == 0) {
    float dt = 1.0f / (1.0f + __expf(-dt_logit[0]));
    consts[288] = 0.1f * dt;  // ESR_ALPHA * dt
  }
  if (h < HN) {
    float lam = lam_p[0];
    float* c = consts + h * 24;
    c[0] = lam * dp_scale[h] * (1.0f / 6.4f);
    c[1] = (1.0f - lam) * logk_scale[h];
    float b = fminf(fmaxf(beta[h], 0.5f), 2.5f);
    c[2] = 0.5f * b;
    c[3] = out_scale[h];
    float m = -1e30f;
    float lw[8];
    bool uni = true;
    for (int t = 0; t < 8; t++) {
      lw[t] = logit_w[h * 8 + t];
      m = fmaxf(m, lw[t]);
      if (log_tau[h * 8 + t] != log_tau[h * 8] || lw[t] != lw[0]) uni = false;
    }
    float s = 0.f;
    float e[8];
    for (int t = 0; t < 8; t++) { e[t] = __expf(lw[t] - m); s += e[t]; }
    for (int t = 0; t < 8; t++) {
      float w = e[t] / s;
      c[12 + t] = log2f(w + 1e-12f);
      float tau = fmaxf(__expf(log_tau[h * 8 + t]), 1e-6f);
      c[4 + t] = 1.0f / (4.0f * tau);
    }
    c[20] = uni ? 1.0f : 8.0f;
  }
}

__global__ __launch_bounds__(256) void zero_kernel(float4* __restrict__ p, int n4) {
  int i = blockIdx.x * 256 + threadIdx.x;
  for (; i < n4; i += gridDim.x * 256) p[i] = make_float4(0.f, 0.f, 0.f, 0.f);
}

// fp32 -> bf16 bulk convert: x, W_qkvg, W_out in one pass (8 elems/thread)
__global__ __launch_bounds__(256) void convert_kernel(
    const float* __restrict__ x, const float* __restrict__ wq,
    const float* __restrict__ wo, unsigned short* __restrict__ xb,
    unsigned short* __restrict__ wqb, unsigned short* __restrict__ wob) {
  int i8 = (blockIdx.x * 256 + threadIdx.x) * 8;
  const float* src;
  unsigned short* dst;
  int off;
  if (i8 < N_XB) { src = x; dst = xb; off = i8; }
  else if (i8 < N_XB + N_WQB) { src = wq; dst = wqb; off = i8 - N_XB; }
  else if (i8 < N_XB + N_WQB + N_WOB) { src = wo; dst = wob; off = i8 - N_XB - N_WQB; }
  else return;
  float4 a = *(const float4*)&src[off];
  float4 b = *(const float4*)&src[off + 4];
  u16x8 u;
  u[0] = f2bf(a.x); u[1] = f2bf(a.y); u[2] = f2bf(a.z); u[3] = f2bf(a.w);
  u[4] = f2bf(b.x); u[5] = f2bf(b.y); u[6] = f2bf(b.z); u[7] = f2bf(b.w);
  *(u16x8*)&dst[off] = u;
}

// qkvg GEMM with fused head-split epilogue. A=xb[1024x768], B=wqb[3072x768]^T.
// Tile 128(M) x 64(N); an N-tile is exactly one (type, head) slab.
// Epilogue: q -> qh*dpc2 bf16; k -> kh; v -> vh + vhT (transposed); g -> rmsnorm -> gh + g2.
__global__ __launch_bounds__(256, 2) void gemm_qkvg_fused(
    const unsigned short* __restrict__ A, const unsigned short* __restrict__ B,
    const float* __restrict__ consts, const float* __restrict__ g_norm_w,
    unsigned short* __restrict__ qh, unsigned short* __restrict__ kh,
    unsigned short* __restrict__ gh, unsigned short* __restrict__ vh,
    unsigned short* __restrict__ vhT, float* __restrict__ g2) {
  const int K = 768;
  __shared__ __align__(16) unsigned short As[128 * 72];
  __shared__ __align__(16) unsigned short Bs[64 * 72];
  int t = threadIdx.x;
  int lane = t & 63, w = t >> 6;
  int quad = lane >> 4, tx = lane & 15;
  int n0 = blockIdx.x * 64, m0 = blockIdx.y * 128;

  f32x4 acc[2][4] = {};
  int r_ = t >> 3, c8 = (t & 7) * 8;

  for (int k0 = 0; k0 < K; k0 += 64) {
    __syncthreads();
#pragma unroll
    for (int rep = 0; rep < 4; rep++) {
      int r = rep * 32 + r_;
      *(u16x8*)&As[r * 72 + c8] = *(const u16x8*)&A[(size_t)(m0 + r) * K + k0 + c8];
    }
#pragma unroll
    for (int rep = 0; rep < 2; rep++) {
      int r = rep * 32 + r_;
      *(u16x8*)&Bs[r * 72 + c8] = *(const u16x8*)&B[(size_t)(n0 + r) * K + k0 + c8];
    }
    __syncthreads();

#pragma unroll
    for (int ks = 0; ks < 2; ks++) {
      bf16x8 af[2];
#pragma unroll
      for (int mi = 0; mi < 2; mi++)
        af[mi] = *(const bf16x8*)&As[(32 * w + mi * 16 + tx) * 72 + ks * 32 + quad * 8];
#pragma unroll
      for (int ni = 0; ni < 4; ni++) {
        bf16x8 bv = *(const bf16x8*)&Bs[(ni * 16 + tx) * 72 + ks * 32 + quad * 8];
#pragma unroll
        for (int mi = 0; mi < 2; mi++)
          acc[mi][ni] = __builtin_amdgcn_mfma_f32_16x16x32_bf16(af[mi], bv, acc[mi][ni], 0, 0, 0);
      }
    }
  }

  // ---- fused epilogue ----
  int typ = n0 / CD;            // 0:q 1:k 2:v 3:g
  int h = (n0 - typ * CD) >> 6;
  unsigned short* Ls = As;      // reuse (128x72)
  __syncthreads();              // K-loop LDS reads complete before overwrite

  if (typ == 3) {
    float gw4[4];
#pragma unroll
    for (int ni = 0; ni < 4; ni++) gw4[ni] = g_norm_w[ni * 16 + tx];
#pragma unroll
    for (int mi = 0; mi < 2; mi++) {
#pragma unroll
      for (int reg = 0; reg < 4; reg++) {
        float s1 = acc[mi][0][reg] * acc[mi][0][reg] + acc[mi][1][reg] * acc[mi][1][reg]
                 + acc[mi][2][reg] * acc[mi][2][reg] + acc[mi][3][reg] * acc[mi][3][reg];
#pragma unroll
        for (int m = 1; m < 16; m <<= 1) s1 += __shfl_xor(s1, m, 64);
        float rms = rsqrtf(s1 * (1.f / 64.f) + 1e-6f);
        int rl = 32 * w + mi * 16 + quad * 4 + reg;
        float s2 = 0.f;
#pragma unroll
        for (int ni = 0; ni < 4; ni++) {
          float v = acc[mi][ni][reg] * rms * gw4[ni];
          unsigned short us = f2bf(v);
          Ls[rl * 72 + ni * 16 + tx] = us;
          float vb = bf2f(us);
          s2 += vb * vb;
        }
#pragma unroll
        for (int m = 1; m < 16; m <<= 1) s2 += __shfl_xor(s2, m, 64);
        if (tx == 0) g2[h * 1024 + m0 + rl] = s2;
      }
    }
    __syncthreads();
#pragma unroll
    for (int rep = 0; rep < 4; rep++) {
      int idx = rep * 256 + t;
      int r = idx >> 3, cc = (idx & 7) * 8;
      *(u16x8*)&gh[(size_t)(h * 1024 + m0 + r) * 64 + cc] = *(const u16x8*)&Ls[r * 72 + cc];
    }
  } else {
    float sc = (typ == 0) ? consts[h * 24] * 1.44269504089f : 1.0f;
#pragma unroll
    for (int mi = 0; mi < 2; mi++)
#pragma unroll
      for (int ni = 0; ni < 4; ni++)
#pragma unroll
        for (int reg = 0; reg < 4; reg++) {
          int rl = 32 * w + mi * 16 + quad * 4 + reg;
          Ls[rl * 72 + ni * 16 + tx] = f2bf(acc[mi][ni][reg] * sc);
        }
    __syncthreads();
    unsigned short* dst = (typ == 0) ? qh : ((typ == 1) ? kh : vh);
#pragma unroll
    for (int rep = 0; rep < 4; rep++) {
      int idx = rep * 256 + t;
      int r = idx >> 3, cc = (idx & 7) * 8;
      *(u16x8*)&dst[(size_t)(h * 1024 + m0 + r) * 64 + cc] = *(const u16x8*)&Ls[r * 72 + cc];
    }
    if (typ == 2) {
#pragma unroll
      for (int rep = 0; rep < 4; rep++) {
        int idx = rep * 256 + t;
        int d = idx >> 4, rc = (idx & 15) * 8;
        u16x8 u;
#pragma unroll
        for (int j = 0; j < 8; j++) u[j] = Ls[(rc + j) * 72 + d];
        *(u16x8*)&vhT[(size_t)(h * 64 + d) * 1024 + m0 + rc] = u;
      }
    }
  }
}

// C[M][N] = A[M][K] @ B[N][K]^T, A,B bf16, C fp32 (generic; used for out-proj).
__global__ __launch_bounds__(256, 2) void gemm_bf16_abT(
    const unsigned short* __restrict__ A, const unsigned short* __restrict__ B,
    float* __restrict__ Cm, int M, int N, int K) {
  __shared__ __align__(16) unsigned short As[128 * 72];
  __shared__ __align__(16) unsigned short Bs[64 * 72];
  int t = threadIdx.x;
  int lane = t & 63, w = t >> 6;
  int quad = lane >> 4, tx = lane & 15;
  int n0 = blockIdx.x * 64, m0 = blockIdx.y * 128;

  f32x4 acc[2][4] = {};
  int r_ = t >> 3, c8 = (t & 7) * 8;

  for (int k0 = 0; k0 < K; k0 += 64) {
    __syncthreads();
#pragma unroll
    for (int rep = 0; rep < 4; rep++) {
      int r = rep * 32 + r_;
      *(u16x8*)&As[r * 72 + c8] = *(const u16x8*)&A[(size_t)(m0 + r) * K + k0 + c8];
    }
#pragma unroll
    for (int rep = 0; rep < 2; rep++) {
      int r = rep * 32 + r_;
      *(u16x8*)&Bs[r * 72 + c8] = *(const u16x8*)&B[(size_t)(n0 + r) * K + k0 + c8];
    }
    __syncthreads();

#pragma unroll
    for (int ks = 0; ks < 2; ks++) {
      bf16x8 af[2];
#pragma unroll
      for (int mi = 0; mi < 2; mi++)
        af[mi] = *(const bf16x8*)&As[(32 * w + mi * 16 + tx) * 72 + ks * 32 + quad * 8];
#pragma unroll
      for (int ni = 0; ni < 4; ni++) {
        bf16x8 bv = *(const bf16x8*)&Bs[(ni * 16 + tx) * 72 + ks * 32 + quad * 8];
#pragma unroll
        for (int mi = 0; mi < 2; mi++)
          acc[mi][ni] = __builtin_amdgcn_mfma_f32_16x16x32_bf16(af[mi], bv, acc[mi][ni], 0, 0, 0);
      }
    }
  }

#pragma unroll
  for (int mi = 0; mi < 2; mi++)
#pragma unroll
    for (int ni = 0; ni < 4; ni++)
#pragma unroll
      for (int reg = 0; reg < 4; reg++) {
        int row = m0 + 32 * w + mi * 16 + quad * 4 + reg;
        Cm[(size_t)row * N + n0 + ni * 16 + tx] = acc[mi][ni][reg];
      }
}

// MFMA flash: block = (head, i-tile of 32 rows, chunk of <=2 j-tiles of 64).
// Gj and V^T overlay one LDS buffer (V prefetched to regs during score phase).
__global__ __launch_bounds__(256, 4) void flash_kernel(
    const unsigned short* __restrict__ qh, const unsigned short* __restrict__ kh,
    const unsigned short* __restrict__ gh, const unsigned short* __restrict__ vhT,
    const float* __restrict__ g2, const float* __restrict__ consts,
    float* __restrict__ Opart, float* __restrict__ lsp, float* __restrict__ pdp) {
  int h = blockIdx.y;
  int uu = 143 - (int)blockIdx.x;  // heavy first
  int it = 0, rem = uu;
  for (it = 0; it < 32; ++it) {
    int njt_ = (it >> 1) + 1;
    int nc = (njt_ + 1) >> 1;
    if (rem < nc) break;
    rem -= nc;
  }
  int njt = (it >> 1) + 1;
  int jt0 = rem * 2;
  int jt1 = (jt0 + 2 < njt) ? (jt0 + 2) : njt;
  bool owns_diag = (jt1 == njt);
  int i0 = it * 32;
  int t = threadIdx.x;
  int lane = t & 63, w = t >> 6;
  int quad = lane >> 4, tx = lane & 15;
  int mi = w >> 1, nb = (w & 1) * 2;

  __shared__ __align__(16) unsigned short Qa[32 * 72];
  __shared__ __align__(16) unsigned short Ga[32 * 72];
  __shared__ __align__(16) unsigned short Ks[64 * 72];
  __shared__ __align__(16) unsigned short GV[64 * 72];  // Gj in score phase, V^T in PV phase
  __shared__ __align__(16) unsigned short psh[32 * 72];
  __shared__ float g2i[32], g2j[64], pdiag[32];

  const float* ch = consts + h * 24;
  float lkc = ch[1], bh2 = ch[2];
  int ntt = (int)ch[20];
  float i4t0 = ch[4];
  float inv4tau[8], logw[8];
#pragma unroll
  for (int tt = 0; tt < 8; tt++) { inv4tau[tt] = ch[4 + tt]; logw[tt] = ch[12 + tt]; }

  {
    int r = t >> 3, c8 = (t & 7) * 8;
    *(u16x8*)&Qa[r * 72 + c8] = *(const u16x8*)&qh[(size_t)(h * 1024 + i0 + r) * 64 + c8];
    *(u16x8*)&Ga[r * 72 + c8] = *(const u16x8*)&gh[(size_t)(h * 1024 + i0 + r) * 64 + c8];
  }
  if (t < 32) { g2i[t] = g2[h * 1024 + i0 + t]; pdiag[t] = 0.f; }
  __syncthreads();

  bf16x8 aq[2], ag[2];
#pragma unroll
  for (int ks = 0; ks < 2; ks++) {
    aq[ks] = *(const bf16x8*)&Qa[(mi * 16 + tx) * 72 + ks * 32 + quad * 8];
    ag[ks] = *(const bf16x8*)&Ga[(mi * 16 + tx) * 72 + ks * 32 + quad * 8];
  }

  f32x4 Oc[2] = {};
  float rowacc[4] = {0.f, 0.f, 0.f, 0.f};
  int r4 = t >> 2, cb = (t & 3) * 16;

  for (int jt = jt0; jt < jt1; jt++) {
    int j0 = jt * 64;
    __syncthreads();  // A: prior PV reads done
    {
      const unsigned short* kp = &kh[(size_t)(h * 1024 + j0 + r4) * 64 + cb];
      const unsigned short* gp = &gh[(size_t)(h * 1024 + j0 + r4) * 64 + cb];
      *(u16x8*)&Ks[r4 * 72 + cb] = *(const u16x8*)kp;
      *(u16x8*)&Ks[r4 * 72 + cb + 8] = *(const u16x8*)(kp + 8);
      *(u16x8*)&GV[r4 * 72 + cb] = *(const u16x8*)gp;
      *(u16x8*)&GV[r4 * 72 + cb + 8] = *(const u16x8*)(gp + 8);
    }
    if (t < 64) g2j[t] = g2[h * 1024 + j0 + t];
    __syncthreads();  // B: staging visible

    // prefetch V for this tile into registers (latency hides under scores)
    u16x8 v0, v1;
    {
      const unsigned short* vp = &vhT[(size_t)(h * 64 + r4) * 1024 + j0 + cb];
      v0 = *(const u16x8*)vp;
      v1 = *(const u16x8*)(vp + 8);
    }

    f32x4 sqk[2] = {}, sgg[2] = {};
#pragma unroll
    for (int ni2 = 0; ni2 < 2; ni2++) {
#pragma unroll
      for (int ks = 0; ks < 2; ks++) {
        bf16x8 bk = *(const bf16x8*)&Ks[((nb + ni2) * 16 + tx) * 72 + ks * 32 + quad * 8];
        sqk[ni2] = __builtin_amdgcn_mfma_f32_16x16x32_bf16(aq[ks], bk, sqk[ni2], 0, 0, 0);
        bf16x8 bg = *(const bf16x8*)&GV[((nb + ni2) * 16 + tx) * 72 + ks * 32 + quad * 8];
        sgg[ni2] = __builtin_amdgcn_mfma_f32_16x16x32_bf16(ag[ks], bg, sgg[ni2], 0, 0, 0);
      }
    }

    float rs[4] = {0.f, 0.f, 0.f, 0.f};
#pragma unroll
    for (int ni2 = 0; ni2 < 2; ni2++) {
      int colg = j0 + (nb + ni2) * 16 + tx;
      float g2jv = g2j[(nb + ni2) * 16 + tx];
#pragma unroll
      for (int reg = 0; reg < 4; reg++) {
        int rowl = mi * 16 + quad * 4 + reg;
        int gi = i0 + rowl;
        float s = fmaxf(g2i[rowl] + g2jv - 2.0f * sgg[ni2][reg], 0.0f);
        float lse2;
        if (ntt == 1) {
          lse2 = -bh2 * __builtin_amdgcn_logf(fmaf(s, i4t0, 1.0f));
        } else {
          float se = 0.f;
#pragma unroll
          for (int tt = 0; tt < 8; tt++) {
            float lv = __builtin_amdgcn_logf(fmaf(s, inv4tau[tt], 1.0f));
            se += __builtin_amdgcn_exp2f(fmaf(-bh2, lv, logw[tt]));
          }
          lse2 = __builtin_amdgcn_logf(se + 1e-30f);
        }
        float b = fmaf(lkc, lse2, sqk[ni2][reg]);  // q pre-scaled by dpc2 in epilogue
        float p = (colg <= gi) ? __builtin_amdgcn_exp2f(b) : 0.0f;
        rs[reg] += p;
        psh[rowl * 72 + (nb + ni2) * 16 + tx] = f2bf(p);
        if (colg == gi) pdiag[rowl] = p;
      }
    }
#pragma unroll
    for (int reg = 0; reg < 4; reg++) {
#pragma unroll
      for (int m = 1; m < 16; m <<= 1) rs[reg] += __shfl_xor(rs[reg], m, 64);
      rowacc[reg] += rs[reg];
    }
    __syncthreads();  // C: GG reads of GV done; psh visible
    *(u16x8*)&GV[r4 * 72 + cb] = v0;
    *(u16x8*)&GV[r4 * 72 + cb + 8] = v1;
    __syncthreads();  // D: V visible

    bf16x8 ap[2];
#pragma unroll
    for (int ks = 0; ks < 2; ks++)
      ap[ks] = *(const bf16x8*)&psh[(mi * 16 + tx) * 72 + ks * 32 + quad * 8];
#pragma unroll
    for (int nd2 = 0; nd2 < 2; nd2++) {
#pragma unroll
      for (int ks = 0; ks < 2; ks++) {
        bf16x8 bv = *(const bf16x8*)&GV[((nb + nd2) * 16 + tx) * 72 + ks * 32 + quad * 8];
        Oc[nd2] = __builtin_amdgcn_mfma_f32_16x16x32_bf16(ap[ks], bv, Oc[nd2], 0, 0, 0);
      }
    }
  }
  __syncthreads();

#pragma unroll
  for (int nd2 = 0; nd2 < 2; nd2++) {
#pragma unroll
    for (int reg = 0; reg < 4; reg++) {
      int row = i0 + mi * 16 + quad * 4 + reg;
      atomicAdd(&Opart[(size_t)(h * 1024 + row) * 64 + (nb + nd2) * 16 + tx], Oc[nd2][reg]);
    }
  }
  if (tx == 0) {
#pragma unroll
    for (int reg = 0; reg < 4; reg++)
      atomicAdd(&lsp[h * 1024 + i0 + mi * 16 + quad * 4 + reg], rowacc[reg]);
  }
  if (owns_diag && t < 32) pdp[h * 1024 + i0 + t] = pdiag[t];
}

// y_i = osc*(c1*(P@v)_i + c2*v_i); writes yb in bf16 for the out-GEMM.
__global__ __launch_bounds__(256) void finalize_kernel(
    const float* __restrict__ Opart, const float* __restrict__ lsp,
    const float* __restrict__ pdp, const unsigned short* __restrict__ vh,
    const float* __restrict__ consts, unsigned short* __restrict__ yb) {
  int h = blockIdx.y;
  int t = threadIdx.x;
  int rl = t >> 4, d4 = t & 15;
  int gi = blockIdx.x * 16 + rl;
  float alpha = consts[288];
  float osc = consts[h * 24 + 3];
  float l = fmaxf(lsp[h * TSEQ + gi], 1e-12f);
  float Pii = pdp[h * TSEQ + gi] / l;
  float inv1p = 1.0f / (1.0f + Pii);
  float c1 = (1.0f - alpha) + alpha * inv1p;
  float c2 = alpha * Pii * inv1p;
  float invl = 1.0f / l;
  float4 Ov = *(const float4*)&Opart[(size_t)(h * 1024 + gi) * 64 + 4 * d4];
  u16x4 vb = *(const u16x4*)&vh[(size_t)(h * 1024 + gi) * 64 + 4 * d4];
  u16x4 o;
  o[0] = f2bf(osc * (c1 * Ov.x * invl + c2 * bf2f(vb[0])));
  o[1] = f2bf(osc * (c1 * Ov.y * invl + c2 * bf2f(vb[1])));
  o[2] = f2bf(osc * (c1 * Ov.z * invl + c2 * bf2f(vb[2])));
  o[3] = f2bf(osc * (c1 * Ov.w * invl + c2 * bf2f(vb[3])));
  *(u16x4*)&yb[(size_t)gi * CD + h * 64 + 4 * d4] = o;
}

extern "C" void kernel_launch(void* const* d_in, const int* in_sizes, int n_in,
                              void* d_out, int out_size, void* d_ws, size_t ws_size,
                              hipStream_t stream) {
  (void)in_sizes; (void)n_in; (void)out_size; (void)ws_size;
  const float* x          = (const float*)d_in[0];
  const float* W_qkvg     = (const float*)d_in[1];
  const float* W_out      = (const float*)d_in[2];
  const float* lam        = (const float*)d_in[3];
  const float* log_tau    = (const float*)d_in[4];
  const float* logit_w    = (const float*)d_in[5];
  const float* beta       = (const float*)d_in[6];
  const float* out_scale  = (const float*)d_in[7];
  const float* dp_scale   = (const float*)d_in[8];
  const float* logk_scale = (const float*)d_in[9];
  const float* dt_logit   = (const float*)d_in[10];
  const float* g_norm_w   = (const float*)d_in[11];
  float* ws = (float*)d_ws;
  unsigned short* qh  = (unsigned short*)(ws + OFF_QH);
  unsigned short* kh  = (unsigned short*)(ws + OFF_KH);
  unsigned short* gh  = (unsigned short*)(ws + OFF_GH);
  unsigned short* vhT = (unsigned short*)(ws + OFF_VHT);
  unsigned short* vh  = (unsigned short*)(ws + OFF_VH);
  float* g2     = ws + OFF_G2;
  unsigned short* yb  = (unsigned short*)(ws + OFF_YB);
  float* consts = ws + OFF_CONSTS;
  float* Opart  = ws + OFF_OPART;
  float* lsp    = ws + OFF_LS;
  float* pdp    = ws + OFF_PD;
  unsigned short* xb  = (unsigned short*)(ws + OFF_XB);
  unsigned short* wqb = (unsigned short*)(ws + OFF_WQB);
  unsigned short* wob = (unsigned short*)(ws + OFF_WOB);
  float* out = (float*)d_out;

  prep_kernel<<<dim3(1), dim3(64), 0, stream>>>(lam, log_tau, logit_w, beta,
                                                out_scale, dp_scale, logk_scale,
                                                dt_logit, consts);
  zero_kernel<<<dim3(512), dim3(256), 0, stream>>>((float4*)Opart, NZERO4);
  convert_kernel<<<dim3((N_XB + N_WQB + N_WOB) / (256 * 8)), dim3(256), 0, stream>>>(
      x, W_qkvg, W_out, xb, wqb, wob);
  gemm_qkvg_fused<<<dim3(48, 8), dim3(256), 0, stream>>>(xb, wqb, consts, g_norm_w,
                                                         qh, kh, gh, vh, vhT, g2);
  flash_kernel<<<dim3(144, 12), dim3(256), 0, stream>>>(qh, kh, gh, vhT, g2, consts,
                                                        Opart, lsp, pdp);
  finalize_kernel<<<dim3(64, 12), dim3(256), 0, stream>>>(Opart, lsp, pdp, vh, consts, yb);
  gemm_bf16_abT<<<dim3(12, 8), dim3(256), 0, stream>>>(yb, wob, out, 1024, 768, 768);
}

// Round 8
// 157.847 us; speedup vs baseline: 1.0341x; 1.0341x over previous
//
#include <hip/hip_runtime.h>
#include <math.h>

#define TSEQ 1024
#define CD   768
#define HN   12
#define DD   64

// workspace float offsets (~43 MB total)
#define OFF_QH     0          // bf16 12*1024*64 -> 393216 floats each
#define OFF_KH     393216
#define OFF_GH     786432
#define OFF_VHT    1179648    // bf16 d-major [H][D][T]
#define OFF_VH     1572864    // bf16 row-major [H][T][D]
#define OFF_G2     1966080    // 12*1024
#define OFF_YB     1978368    // bf16 1024*768
#define OFF_CONSTS 2371584    // 512
#define OFF_OPART  2372096    // 8 slices * 786432 = 6291456
#define OFF_LS     8663552    // 8 slices * 12288  = 98304
#define OFF_PD     8761856    // 12288
#define OFF_XB     8774144    // bf16 1024*768
#define OFF_WQB    9167360    // bf16 3072*768
#define OFF_WOB    10347008   // bf16 768*768 (end 10641920 floats)

#define N_XB  786432
#define N_WQB 2359296
#define N_WOB 589824

typedef __bf16 bf16x8 __attribute__((ext_vector_type(8)));
typedef float  f32x4  __attribute__((ext_vector_type(4)));
typedef unsigned short u16x8 __attribute__((ext_vector_type(8)));
typedef unsigned short u16x4 __attribute__((ext_vector_type(4)));

__device__ inline unsigned short f2bf(float f) {
  unsigned int u = __float_as_uint(f);
  return (unsigned short)((u + 0x7fffu + ((u >> 16) & 1u)) >> 16);  // RNE
}
__device__ inline float bf2f(unsigned short u) {
  return __uint_as_float((unsigned)u << 16);
}

// consts per head (stride 24): [0]=lam*dp_scale/6.4, [1]=(1-lam)*logk_scale,
// [2]=clip(beta)/2, [3]=out_scale, [4..11]=1/(4*tau), [12..19]=log2(w+1e-12),
// [20]=ntt (1 if uniform tau & w, else 8). alpha at [288].

__global__ __launch_bounds__(64) void prep_kernel(
    const float* __restrict__ lam_p, const float* __restrict__ log_tau,
    const float* __restrict__ logit_w, const float* __restrict__ beta,
    const float* __restrict__ out_scale, const float* __restrict__ dp_scale,
    const float* __restrict__ logk_scale, const float* __restrict__ dt_logit,
    float* __restrict__ consts) {
  int h = threadIdx.x;
  if (h == 0) {
    float dt = 1.0f / (1.0f + __expf(-dt_logit[0]));
    consts[288] = 0.1f * dt;  // ESR_ALPHA * dt
  }
  if (h < HN) {
    float lam = lam_p[0];
    float* c = consts + h * 24;
    c[0] = lam * dp_scale[h] * (1.0f / 6.4f);
    c[1] = (1.0f - lam) * logk_scale[h];
    float b = fminf(fmaxf(beta[h], 0.5f), 2.5f);
    c[2] = 0.5f * b;
    c[3] = out_scale[h];
    float m = -1e30f;
    float lw[8];
    bool uni = true;
    for (int t = 0; t < 8; t++) {
      lw[t] = logit_w[h * 8 + t];
      m = fmaxf(m, lw[t]);
      if (log_tau[h * 8 + t] != log_tau[h * 8] || lw[t] != lw[0]) uni = false;
    }
    float s = 0.f;
    float e[8];
    for (int t = 0; t < 8; t++) { e[t] = __expf(lw[t] - m); s += e[t]; }
    for (int t = 0; t < 8; t++) {
      float w = e[t] / s;
      c[12 + t] = log2f(w + 1e-12f);
      float tau = fmaxf(__expf(log_tau[h * 8 + t]), 1e-6f);
      c[4 + t] = 1.0f / (4.0f * tau);
    }
    c[20] = uni ? 1.0f : 8.0f;
  }
}

// fp32 -> bf16 bulk convert: x, W_qkvg, W_out in one pass (8 elems/thread)
__global__ __launch_bounds__(256) void convert_kernel(
    const float* __restrict__ x, const float* __restrict__ wq,
    const float* __restrict__ wo, unsigned short* __restrict__ xb,
    unsigned short* __restrict__ wqb, unsigned short* __restrict__ wob) {
  int i8 = (blockIdx.x * 256 + threadIdx.x) * 8;
  const float* src;
  unsigned short* dst;
  int off;
  if (i8 < N_XB) { src = x; dst = xb; off = i8; }
  else if (i8 < N_XB + N_WQB) { src = wq; dst = wqb; off = i8 - N_XB; }
  else if (i8 < N_XB + N_WQB + N_WOB) { src = wo; dst = wob; off = i8 - N_XB - N_WQB; }
  else return;
  float4 a = *(const float4*)&src[off];
  float4 b = *(const float4*)&src[off + 4];
  u16x8 u;
  u[0] = f2bf(a.x); u[1] = f2bf(a.y); u[2] = f2bf(a.z); u[3] = f2bf(a.w);
  u[4] = f2bf(b.x); u[5] = f2bf(b.y); u[6] = f2bf(b.z); u[7] = f2bf(b.w);
  *(u16x8*)&dst[off] = u;
}

// qkvg GEMM with fused head-split epilogue. A=xb[1024x768], B=wqb[3072x768]^T.
// Tile 128(M) x 64(N); an N-tile is exactly one (type, head) slab.
// Epilogue: q -> qh*dpc2 bf16; k -> kh; v -> vh + vhT (transposed); g -> rmsnorm -> gh + g2.
__global__ __launch_bounds__(256, 2) void gemm_qkvg_fused(
    const unsigned short* __restrict__ A, const unsigned short* __restrict__ B,
    const float* __restrict__ consts, const float* __restrict__ g_norm_w,
    unsigned short* __restrict__ qh, unsigned short* __restrict__ kh,
    unsigned short* __restrict__ gh, unsigned short* __restrict__ vh,
    unsigned short* __restrict__ vhT, float* __restrict__ g2) {
  const int K = 768;
  __shared__ __align__(16) unsigned short As[128 * 72];
  __shared__ __align__(16) unsigned short Bs[64 * 72];
  int t = threadIdx.x;
  int lane = t & 63, w = t >> 6;
  int quad = lane >> 4, tx = lane & 15;
  int n0 = blockIdx.x * 64, m0 = blockIdx.y * 128;

  f32x4 acc[2][4] = {};
  int r_ = t >> 3, c8 = (t & 7) * 8;

  for (int k0 = 0; k0 < K; k0 += 64) {
    __syncthreads();
#pragma unroll
    for (int rep = 0; rep < 4; rep++) {
      int r = rep * 32 + r_;
      *(u16x8*)&As[r * 72 + c8] = *(const u16x8*)&A[(size_t)(m0 + r) * K + k0 + c8];
    }
#pragma unroll
    for (int rep = 0; rep < 2; rep++) {
      int r = rep * 32 + r_;
      *(u16x8*)&Bs[r * 72 + c8] = *(const u16x8*)&B[(size_t)(n0 + r) * K + k0 + c8];
    }
    __syncthreads();

#pragma unroll
    for (int ks = 0; ks < 2; ks++) {
      bf16x8 af[2];
#pragma unroll
      for (int mi = 0; mi < 2; mi++)
        af[mi] = *(const bf16x8*)&As[(32 * w + mi * 16 + tx) * 72 + ks * 32 + quad * 8];
#pragma unroll
      for (int ni = 0; ni < 4; ni++) {
        bf16x8 bv = *(const bf16x8*)&Bs[(ni * 16 + tx) * 72 + ks * 32 + quad * 8];
#pragma unroll
        for (int mi = 0; mi < 2; mi++)
          acc[mi][ni] = __builtin_amdgcn_mfma_f32_16x16x32_bf16(af[mi], bv, acc[mi][ni], 0, 0, 0);
      }
    }
  }

  // ---- fused epilogue ----
  int typ = n0 / CD;            // 0:q 1:k 2:v 3:g
  int h = (n0 - typ * CD) >> 6;
  unsigned short* Ls = As;      // reuse (128x72)
  __syncthreads();              // K-loop LDS reads complete before overwrite

  if (typ == 3) {
    float gw4[4];
#pragma unroll
    for (int ni = 0; ni < 4; ni++) gw4[ni] = g_norm_w[ni * 16 + tx];
#pragma unroll
    for (int mi = 0; mi < 2; mi++) {
#pragma unroll
      for (int reg = 0; reg < 4; reg++) {
        float s1 = acc[mi][0][reg] * acc[mi][0][reg] + acc[mi][1][reg] * acc[mi][1][reg]
                 + acc[mi][2][reg] * acc[mi][2][reg] + acc[mi][3][reg] * acc[mi][3][reg];
#pragma unroll
        for (int m = 1; m < 16; m <<= 1) s1 += __shfl_xor(s1, m, 64);
        float rms = rsqrtf(s1 * (1.f / 64.f) + 1e-6f);
        int rl = 32 * w + mi * 16 + quad * 4 + reg;
        float s2 = 0.f;
#pragma unroll
        for (int ni = 0; ni < 4; ni++) {
          float v = acc[mi][ni][reg] * rms * gw4[ni];
          unsigned short us = f2bf(v);
          Ls[rl * 72 + ni * 16 + tx] = us;
          float vb = bf2f(us);
          s2 += vb * vb;
        }
#pragma unroll
        for (int m = 1; m < 16; m <<= 1) s2 += __shfl_xor(s2, m, 64);
        if (tx == 0) g2[h * 1024 + m0 + rl] = s2;
      }
    }
    __syncthreads();
#pragma unroll
    for (int rep = 0; rep < 4; rep++) {
      int idx = rep * 256 + t;
      int r = idx >> 3, cc = (idx & 7) * 8;
      *(u16x8*)&gh[(size_t)(h * 1024 + m0 + r) * 64 + cc] = *(const u16x8*)&Ls[r * 72 + cc];
    }
  } else {
    float sc = (typ == 0) ? consts[h * 24] * 1.44269504089f : 1.0f;
#pragma unroll
    for (int mi = 0; mi < 2; mi++)
#pragma unroll
      for (int ni = 0; ni < 4; ni++)
#pragma unroll
        for (int reg = 0; reg < 4; reg++) {
          int rl = 32 * w + mi * 16 + quad * 4 + reg;
          Ls[rl * 72 + ni * 16 + tx] = f2bf(acc[mi][ni][reg] * sc);
        }
    __syncthreads();
    unsigned short* dst = (typ == 0) ? qh : ((typ == 1) ? kh : vh);
#pragma unroll
    for (int rep = 0; rep < 4; rep++) {
      int idx = rep * 256 + t;
      int r = idx >> 3, cc = (idx & 7) * 8;
      *(u16x8*)&dst[(size_t)(h * 1024 + m0 + r) * 64 + cc] = *(const u16x8*)&Ls[r * 72 + cc];
    }
    if (typ == 2) {
#pragma unroll
      for (int rep = 0; rep < 4; rep++) {
        int idx = rep * 256 + t;
        int d = idx >> 4, rc = (idx & 15) * 8;
        u16x8 u;
#pragma unroll
        for (int j = 0; j < 8; j++) u[j] = Ls[(rc + j) * 72 + d];
        *(u16x8*)&vhT[(size_t)(h * 64 + d) * 1024 + m0 + rc] = u;
      }
    }
  }
}

// C[M][N] = A[M][K] @ B[N][K]^T, A,B bf16, C fp32 (generic; used for out-proj).
__global__ __launch_bounds__(256, 2) void gemm_bf16_abT(
    const unsigned short* __restrict__ A, const unsigned short* __restrict__ B,
    float* __restrict__ Cm, int M, int N, int K) {
  __shared__ __align__(16) unsigned short As[128 * 72];
  __shared__ __align__(16) unsigned short Bs[64 * 72];
  int t = threadIdx.x;
  int lane = t & 63, w = t >> 6;
  int quad = lane >> 4, tx = lane & 15;
  int n0 = blockIdx.x * 64, m0 = blockIdx.y * 128;

  f32x4 acc[2][4] = {};
  int r_ = t >> 3, c8 = (t & 7) * 8;

  for (int k0 = 0; k0 < K; k0 += 64) {
    __syncthreads();
#pragma unroll
    for (int rep = 0; rep < 4; rep++) {
      int r = rep * 32 + r_;
      *(u16x8*)&As[r * 72 + c8] = *(const u16x8*)&A[(size_t)(m0 + r) * K + k0 + c8];
    }
#pragma unroll
    for (int rep = 0; rep < 2; rep++) {
      int r = rep * 32 + r_;
      *(u16x8*)&Bs[r * 72 + c8] = *(const u16x8*)&B[(size_t)(n0 + r) * K + k0 + c8];
    }
    __syncthreads();

#pragma unroll
    for (int ks = 0; ks < 2; ks++) {
      bf16x8 af[2];
#pragma unroll
      for (int mi = 0; mi < 2; mi++)
        af[mi] = *(const bf16x8*)&As[(32 * w + mi * 16 + tx) * 72 + ks * 32 + quad * 8];
#pragma unroll
      for (int ni = 0; ni < 4; ni++) {
        bf16x8 bv = *(const bf16x8*)&Bs[(ni * 16 + tx) * 72 + ks * 32 + quad * 8];
#pragma unroll
        for (int mi = 0; mi < 2; mi++)
          acc[mi][ni] = __builtin_amdgcn_mfma_f32_16x16x32_bf16(af[mi], bv, acc[mi][ni], 0, 0, 0);
      }
    }
  }

#pragma unroll
  for (int mi = 0; mi < 2; mi++)
#pragma unroll
    for (int ni = 0; ni < 4; ni++)
#pragma unroll
      for (int reg = 0; reg < 4; reg++) {
        int row = m0 + 32 * w + mi * 16 + quad * 4 + reg;
        Cm[(size_t)row * N + n0 + ni * 16 + tx] = acc[mi][ni][reg];
      }
}

// MFMA flash (R6 structure: 3 barriers/j-tile, no atomics).
// Block = (head, i-tile of 32 rows, chunk rem of <=2 j-tiles). Partial O and
// row-sums go to per-chunk slices; finalize sums them.
__global__ __launch_bounds__(256, 3) void flash_kernel(
    const unsigned short* __restrict__ qh, const unsigned short* __restrict__ kh,
    const unsigned short* __restrict__ gh, const unsigned short* __restrict__ vhT,
    const float* __restrict__ g2, const float* __restrict__ consts,
    float* __restrict__ Opart, float* __restrict__ lsp, float* __restrict__ pdp) {
  int h = blockIdx.y;
  int uu = 143 - (int)blockIdx.x;  // heavy first
  int it = 0, rem = uu;
  for (it = 0; it < 32; ++it) {
    int njt_ = (it >> 1) + 1;
    int nc = (njt_ + 1) >> 1;
    if (rem < nc) break;
    rem -= nc;
  }
  int njt = (it >> 1) + 1;
  int jt0 = rem * 2;
  int jt1 = (jt0 + 2 < njt) ? (jt0 + 2) : njt;
  bool owns_diag = (jt1 == njt);
  int i0 = it * 32;
  int t = threadIdx.x;
  int lane = t & 63, w = t >> 6;
  int quad = lane >> 4, tx = lane & 15;
  int mi = w >> 1, nb = (w & 1) * 2;

  __shared__ __align__(16) unsigned short Qa[32 * 72];
  __shared__ __align__(16) unsigned short Ga[32 * 72];
  __shared__ __align__(16) unsigned short Ks[64 * 72];
  __shared__ __align__(16) unsigned short Gjs[64 * 72];
  __shared__ __align__(16) unsigned short Vt[64 * 72];
  __shared__ __align__(16) unsigned short psh[32 * 72];
  __shared__ float g2i[32], g2j[64], pdiag[32], lsum[32];

  const float* ch = consts + h * 24;
  float lkc = ch[1], bh2 = ch[2];
  int ntt = (int)ch[20];
  float i4t0 = ch[4];
  float inv4tau[8], logw[8];
#pragma unroll
  for (int tt = 0; tt < 8; tt++) { inv4tau[tt] = ch[4 + tt]; logw[tt] = ch[12 + tt]; }

  {
    int r = t >> 3, c8 = (t & 7) * 8;
    *(u16x8*)&Qa[r * 72 + c8] = *(const u16x8*)&qh[(size_t)(h * 1024 + i0 + r) * 64 + c8];
    *(u16x8*)&Ga[r * 72 + c8] = *(const u16x8*)&gh[(size_t)(h * 1024 + i0 + r) * 64 + c8];
  }
  if (t < 32) { g2i[t] = g2[h * 1024 + i0 + t]; pdiag[t] = 0.f; }
  __syncthreads();

  bf16x8 aq[2], ag[2];
#pragma unroll
  for (int ks = 0; ks < 2; ks++) {
    aq[ks] = *(const bf16x8*)&Qa[(mi * 16 + tx) * 72 + ks * 32 + quad * 8];
    ag[ks] = *(const bf16x8*)&Ga[(mi * 16 + tx) * 72 + ks * 32 + quad * 8];
  }

  f32x4 Oc[2] = {};
  float rowacc[4] = {0.f, 0.f, 0.f, 0.f};
  int r4 = t >> 2, cb = (t & 3) * 16;

  for (int jt = jt0; jt < jt1; jt++) {
    int j0 = jt * 64;
    __syncthreads();  // A: prior tile reads done
    {
      const unsigned short* kp = &kh[(size_t)(h * 1024 + j0 + r4) * 64 + cb];
      const unsigned short* gp = &gh[(size_t)(h * 1024 + j0 + r4) * 64 + cb];
      const unsigned short* vp = &vhT[(size_t)(h * 64 + r4) * 1024 + j0 + cb];
      *(u16x8*)&Ks[r4 * 72 + cb] = *(const u16x8*)kp;
      *(u16x8*)&Ks[r4 * 72 + cb + 8] = *(const u16x8*)(kp + 8);
      *(u16x8*)&Gjs[r4 * 72 + cb] = *(const u16x8*)gp;
      *(u16x8*)&Gjs[r4 * 72 + cb + 8] = *(const u16x8*)(gp + 8);
      *(u16x8*)&Vt[r4 * 72 + cb] = *(const u16x8*)vp;
      *(u16x8*)&Vt[r4 * 72 + cb + 8] = *(const u16x8*)(vp + 8);
    }
    if (t < 64) g2j[t] = g2[h * 1024 + j0 + t];
    __syncthreads();  // B: staging visible

    f32x4 sqk[2] = {}, sgg[2] = {};
#pragma unroll
    for (int ni2 = 0; ni2 < 2; ni2++) {
#pragma unroll
      for (int ks = 0; ks < 2; ks++) {
        bf16x8 bk = *(const bf16x8*)&Ks[((nb + ni2) * 16 + tx) * 72 + ks * 32 + quad * 8];
        sqk[ni2] = __builtin_amdgcn_mfma_f32_16x16x32_bf16(aq[ks], bk, sqk[ni2], 0, 0, 0);
        bf16x8 bg = *(const bf16x8*)&Gjs[((nb + ni2) * 16 + tx) * 72 + ks * 32 + quad * 8];
        sgg[ni2] = __builtin_amdgcn_mfma_f32_16x16x32_bf16(ag[ks], bg, sgg[ni2], 0, 0, 0);
      }
    }

    float rs[4] = {0.f, 0.f, 0.f, 0.f};
#pragma unroll
    for (int ni2 = 0; ni2 < 2; ni2++) {
      int colg = j0 + (nb + ni2) * 16 + tx;
      float g2jv = g2j[(nb + ni2) * 16 + tx];
#pragma unroll
      for (int reg = 0; reg < 4; reg++) {
        int rowl = mi * 16 + quad * 4 + reg;
        int gi = i0 + rowl;
        float s = fmaxf(g2i[rowl] + g2jv - 2.0f * sgg[ni2][reg], 0.0f);
        float lse2;
        if (ntt == 1) {
          lse2 = -bh2 * __builtin_amdgcn_logf(fmaf(s, i4t0, 1.0f));
        } else {
          float se = 0.f;
#pragma unroll
          for (int tt = 0; tt < 8; tt++) {
            float lv = __builtin_amdgcn_logf(fmaf(s, inv4tau[tt], 1.0f));
            se += __builtin_amdgcn_exp2f(fmaf(-bh2, lv, logw[tt]));
          }
          lse2 = __builtin_amdgcn_logf(se + 1e-30f);
        }
        float b = fmaf(lkc, lse2, sqk[ni2][reg]);  // q pre-scaled by dpc2 in epilogue
        float p = (colg <= gi) ? __builtin_amdgcn_exp2f(b) : 0.0f;
        rs[reg] += p;
        psh[rowl * 72 + (nb + ni2) * 16 + tx] = f2bf(p);
        if (colg == gi) pdiag[rowl] = p;
      }
    }
#pragma unroll
    for (int reg = 0; reg < 4; reg++) {
#pragma unroll
      for (int m = 1; m < 16; m <<= 1) rs[reg] += __shfl_xor(rs[reg], m, 64);
      rowacc[reg] += rs[reg];
    }
    __syncthreads();  // C: psh visible

    bf16x8 ap[2];
#pragma unroll
    for (int ks = 0; ks < 2; ks++)
      ap[ks] = *(const bf16x8*)&psh[(mi * 16 + tx) * 72 + ks * 32 + quad * 8];
#pragma unroll
    for (int nd2 = 0; nd2 < 2; nd2++) {
#pragma unroll
      for (int ks = 0; ks < 2; ks++) {
        bf16x8 bv = *(const bf16x8*)&Vt[((nb + nd2) * 16 + tx) * 72 + ks * 32 + quad * 8];
        Oc[nd2] = __builtin_amdgcn_mfma_f32_16x16x32_bf16(ap[ks], bv, Oc[nd2], 0, 0, 0);
      }
    }
  }

  // combine the two waves sharing an mi-strip, then plain stores to slice `rem`
  if ((w & 1) == 0 && tx == 0) {
#pragma unroll
    for (int reg = 0; reg < 4; reg++) lsum[mi * 16 + quad * 4 + reg] = rowacc[reg];
  }
  __syncthreads();
  if ((w & 1) == 1 && tx == 0) {
#pragma unroll
    for (int reg = 0; reg < 4; reg++) {
      int rowl = mi * 16 + quad * 4 + reg;
      lsp[(size_t)(rem * HN + h) * 1024 + i0 + rowl] = lsum[rowl] + rowacc[reg];
    }
  }
  float* Ob = Opart + (size_t)((rem * HN + h) * 1024 + i0) * 64;
#pragma unroll
  for (int nd2 = 0; nd2 < 2; nd2++) {
#pragma unroll
    for (int reg = 0; reg < 4; reg++) {
      int rowl = mi * 16 + quad * 4 + reg;
      Ob[rowl * 64 + (nb + nd2) * 16 + tx] = Oc[nd2][reg];
    }
  }
  if (owns_diag && t < 32) pdp[h * 1024 + i0 + t] = pdiag[t];
}

// Sum chunk slices; y_i = osc*(c1*(P@v)_i + c2*v_i); write yb bf16.
__global__ __launch_bounds__(256) void finalize_kernel(
    const float* __restrict__ Opart, const float* __restrict__ lsp,
    const float* __restrict__ pdp, const unsigned short* __restrict__ vh,
    const float* __restrict__ consts, unsigned short* __restrict__ yb) {
  int h = blockIdx.y;
  int t = threadIdx.x;
  int rl = t >> 4, d4 = t & 15;
  int gi = blockIdx.x * 16 + rl;
  int it = gi >> 5;
  int nc = (((it >> 1) + 1) + 1) >> 1;  // chunks for this i-tile
  float alpha = consts[288];
  float osc = consts[h * 24 + 3];
  float4 Ov = make_float4(0.f, 0.f, 0.f, 0.f);
  float l = 0.f;
  for (int c = 0; c < nc; c++) {
    float4 p = *(const float4*)&Opart[(size_t)((c * HN + h) * 1024 + gi) * 64 + 4 * d4];
    Ov.x += p.x; Ov.y += p.y; Ov.z += p.z; Ov.w += p.w;
    l += lsp[(size_t)(c * HN + h) * 1024 + gi];
  }
  l = fmaxf(l, 1e-12f);
  float Pii = pdp[h * TSEQ + gi] / l;
  float inv1p = 1.0f / (1.0f + Pii);
  float c1 = (1.0f - alpha) + alpha * inv1p;
  float c2 = alpha * Pii * inv1p;
  float invl = 1.0f / l;
  u16x4 vb = *(const u16x4*)&vh[(size_t)(h * 1024 + gi) * 64 + 4 * d4];
  u16x4 o;
  o[0] = f2bf(osc * (c1 * Ov.x * invl + c2 * bf2f(vb[0])));
  o[1] = f2bf(osc * (c1 * Ov.y * invl + c2 * bf2f(vb[1])));
  o[2] = f2bf(osc * (c1 * Ov.z * invl + c2 * bf2f(vb[2])));
  o[3] = f2bf(osc * (c1 * Ov.w * invl + c2 * bf2f(vb[3])));
  *(u16x4*)&yb[(size_t)gi * CD + h * 64 + 4 * d4] = o;
}

extern "C" void kernel_launch(void* const* d_in, const int* in_sizes, int n_in,
                              void* d_out, int out_size, void* d_ws, size_t ws_size,
                              hipStream_t stream) {
  (void)in_sizes; (void)n_in; (void)out_size; (void)ws_size;
  const float* x          = (const float*)d_in[0];
  const float* W_qkvg     = (const float*)d_in[1];
  const float* W_out      = (const float*)d_in[2];
  const float* lam        = (const float*)d_in[3];
  const float* log_tau    = (const float*)d_in[4];
  const float* logit_w    = (const float*)d_in[5];
  const float* beta       = (const float*)d_in[6];
  const float* out_scale  = (const float*)d_in[7];
  const float* dp_scale   = (const float*)d_in[8];
  const float* logk_scale = (const float*)d_in[9];
  const float* dt_logit   = (const float*)d_in[10];
  const float* g_norm_w   = (const float*)d_in[11];
  float* ws = (float*)d_ws;
  unsigned short* qh  = (unsigned short*)(ws + OFF_QH);
  unsigned short* kh  = (unsigned short*)(ws + OFF_KH);
  unsigned short* gh  = (unsigned short*)(ws + OFF_GH);
  unsigned short* vhT = (unsigned short*)(ws + OFF_VHT);
  unsigned short* vh  = (unsigned short*)(ws + OFF_VH);
  float* g2     = ws + OFF_G2;
  unsigned short* yb  = (unsigned short*)(ws + OFF_YB);
  float* consts = ws + OFF_CONSTS;
  float* Opart  = ws + OFF_OPART;
  float* lsp    = ws + OFF_LS;
  float* pdp    = ws + OFF_PD;
  unsigned short* xb  = (unsigned short*)(ws + OFF_XB);
  unsigned short* wqb = (unsigned short*)(ws + OFF_WQB);
  unsigned short* wob = (unsigned short*)(ws + OFF_WOB);
  float* out = (float*)d_out;

  prep_kernel<<<dim3(1), dim3(64), 0, stream>>>(lam, log_tau, logit_w, beta,
                                                out_scale, dp_scale, logk_scale,
                                                dt_logit, consts);
  convert_kernel<<<dim3((N_XB + N_WQB + N_WOB) / (256 * 8)), dim3(256), 0, stream>>>(
      x, W_qkvg, W_out, xb, wqb, wob);
  gemm_qkvg_fused<<<dim3(48, 8), dim3(256), 0, stream>>>(xb, wqb, consts, g_norm_w,
                                                         qh, kh, gh, vh, vhT, g2);
  flash_kernel<<<dim3(144, 12), dim3(256), 0, stream>>>(qh, kh, gh, vhT, g2, consts,
                                                        Opart, lsp, pdp);
  finalize_kernel<<<dim3(64, 12), dim3(256), 0, stream>>>(Opart, lsp, pdp, vh, consts, yb);
  gemm_bf16_abT<<<dim3(12, 8), dim3(256), 0, stream>>>(yb, wob, out, 1024, 768, 768);
}

// Round 9
// 156.181 us; speedup vs baseline: 1.0451x; 1.0107x over previous
//
#include <hip/hip_runtime.h>
#include <math.h>

#define TSEQ 1024
#define CD   768
#define HN   12
#define DD   64

// workspace float offsets
#define OFF_QH     0          // bf16 12*1024*64 -> 393216 floats each
#define OFF_KH     393216
#define OFF_GH     786432
#define OFF_VHT    1179648    // bf16 d-major [H][D][T]
#define OFF_VH     1572864    // bf16 row-major [H][T][D]
#define OFF_G2     1966080    // 12*1024
#define OFF_YB     1978368    // bf16 1024*768 (MFMA-frag swizzled)
#define OFF_CONSTS 2371584    // 512
#define OFF_OPART  2372096    // 8 slices * 786432 = 6291456
#define OFF_LS     8663552    // 8 slices * 12288
#define OFF_PD     8761856    // 12288
#define OFF_XB     8774144    // bf16 1024*768 swizzled
#define OFF_WQB    9167360    // bf16 3072*768 swizzled
#define OFF_WOB    10347008   // bf16 768*768 swizzled

#define NG_X  98304           // 1024/16 * 24 * 64
#define NG_WQ 294912          // 3072/16 * 24 * 64
#define NG_WO 73728           // 768/16 * 24 * 64

typedef __bf16 bf16x8 __attribute__((ext_vector_type(8)));
typedef float  f32x4  __attribute__((ext_vector_type(4)));
typedef unsigned short u16x8 __attribute__((ext_vector_type(8)));
typedef unsigned short u16x4 __attribute__((ext_vector_type(4)));

__device__ inline unsigned short f2bf(float f) {
  unsigned int u = __float_as_uint(f);
  return (unsigned short)((u + 0x7fffu + ((u >> 16) & 1u)) >> 16);  // RNE
}
__device__ inline float bf2f(unsigned short u) {
  return __uint_as_float((unsigned)u << 16);
}

// consts per head (stride 24): [0]=lam*dp_scale/6.4, [1]=(1-lam)*logk_scale,
// [2]=clip(beta)/2, [3]=out_scale, [4..11]=1/(4*tau), [12..19]=log2(w+1e-12),
// [20]=ntt. alpha at [288].

__global__ __launch_bounds__(64) void prep_kernel(
    const float* __restrict__ lam_p, const float* __restrict__ log_tau,
    const float* __restrict__ logit_w, const float* __restrict__ beta,
    const float* __restrict__ out_scale, const float* __restrict__ dp_scale,
    const float* __restrict__ logk_scale, const float* __restrict__ dt_logit,
    float* __restrict__ consts) {
  int h = threadIdx.x;
  if (h == 0) {
    float dt = 1.0f / (1.0f + __expf(-dt_logit[0]));
    consts[288] = 0.1f * dt;  // ESR_ALPHA * dt
  }
  if (h < HN) {
    float lam = lam_p[0];
    float* c = consts + h * 24;
    c[0] = lam * dp_scale[h] * (1.0f / 6.4f);
    c[1] = (1.0f - lam) * logk_scale[h];
    float b = fminf(fmaxf(beta[h], 0.5f), 2.5f);
    c[2] = 0.5f * b;
    c[3] = out_scale[h];
    float m = -1e30f;
    float lw[8];
    bool uni = true;
    for (int t = 0; t < 8; t++) {
      lw[t] = logit_w[h * 8 + t];
      m = fmaxf(m, lw[t]);
      if (log_tau[h * 8 + t] != log_tau[h * 8] || lw[t] != lw[0]) uni = false;
    }
    float s = 0.f;
    float e[8];
    for (int t = 0; t < 8; t++) { e[t] = __expf(lw[t] - m); s += e[t]; }
    for (int t = 0; t < 8; t++) {
      float w = e[t] / s;
      c[12 + t] = log2f(w + 1e-12f);
      float tau = fmaxf(__expf(log_tau[h * 8 + t]), 1e-6f);
      c[4 + t] = 1.0f / (4.0f * tau);
    }
    c[20] = uni ? 1.0f : 8.0f;
  }
}

// fp32 -> bf16 convert + MFMA-fragment swizzle for x, W_qkvg, W_out (K=768).
// swz[((t16*24+kb)*64+lane)*8+j] = M[t16*16+(lane&15)][kb*32+(lane>>4)*8+j]
__global__ __launch_bounds__(256) void convert_kernel(
    const float* __restrict__ x, const float* __restrict__ wq,
    const float* __restrict__ wo, unsigned short* __restrict__ swzA,
    unsigned short* __restrict__ swzWQ, unsigned short* __restrict__ swzWO) {
  int g = blockIdx.x * 256 + threadIdx.x;
  const float* src;
  unsigned short* dst;
  int lg;
  if (g < NG_X) { src = x; dst = swzA; lg = g; }
  else if (g < NG_X + NG_WQ) { src = wq; dst = swzWQ; lg = g - NG_X; }
  else if (g < NG_X + NG_WQ + NG_WO) { src = wo; dst = swzWO; lg = g - NG_X - NG_WQ; }
  else return;
  int lane = lg & 63;
  int kb = (lg >> 6) % 24;
  int t16 = lg / (64 * 24);
  int row = t16 * 16 + (lane & 15);
  int col = kb * 32 + (lane >> 4) * 8;
  const float* s = &src[(size_t)row * 768 + col];
  float4 a = *(const float4*)s;
  float4 b = *(const float4*)(s + 4);
  u16x8 u;
  u[0] = f2bf(a.x); u[1] = f2bf(a.y); u[2] = f2bf(a.z); u[3] = f2bf(a.w);
  u[4] = f2bf(b.x); u[5] = f2bf(b.y); u[6] = f2bf(b.z); u[7] = f2bf(b.w);
  *(u16x8*)&dst[(size_t)lg * 8] = u;
}

// LDS-free qkvg GEMM on swizzled fragments + fused per-wave head-split epilogue.
// Block = 4 waves, tile 128(M)x64(N), grid (48, 8). n-tile = (typ, head) slab.
__global__ __launch_bounds__(256) void gemm_frag_qkvg(
    const unsigned short* __restrict__ swzA, const unsigned short* __restrict__ swzB,
    const float* __restrict__ consts, const float* __restrict__ g_norm_w,
    unsigned short* __restrict__ qh, unsigned short* __restrict__ kh,
    unsigned short* __restrict__ gh, unsigned short* __restrict__ vh,
    unsigned short* __restrict__ vhT, float* __restrict__ g2) {
  __shared__ __align__(16) unsigned short Ls[128 * 72];
  int t = threadIdx.x, lane = t & 63, w = t >> 6;
  int quad = lane >> 4, tx = lane & 15;
  int ntile = blockIdx.x;            // 0..47
  int m0 = blockIdx.y * 128;
  int nt0 = ntile * 4;               // 16-col subtiles
  int mt0 = blockIdx.y * 8 + w * 2;  // this wave's 16-row subtiles

  f32x4 acc[2][4] = {};
#pragma unroll 2
  for (int kb = 0; kb < 24; kb++) {
    bf16x8 a0 = *(const bf16x8*)&swzA[((size_t)((mt0 + 0) * 24 + kb) * 64 + lane) * 8];
    bf16x8 a1 = *(const bf16x8*)&swzA[((size_t)((mt0 + 1) * 24 + kb) * 64 + lane) * 8];
#pragma unroll
    for (int ni = 0; ni < 4; ni++) {
      bf16x8 b = *(const bf16x8*)&swzB[((size_t)((nt0 + ni) * 24 + kb) * 64 + lane) * 8];
      acc[0][ni] = __builtin_amdgcn_mfma_f32_16x16x32_bf16(a0, b, acc[0][ni], 0, 0, 0);
      acc[1][ni] = __builtin_amdgcn_mfma_f32_16x16x32_bf16(a1, b, acc[1][ni], 0, 0, 0);
    }
  }

  // per-wave epilogue (no cross-wave LDS sharing)
  int typ = ntile / 12;
  int h = ntile % 12;
  unsigned short* Lw = Ls + w * (32 * 72);
  int mrow0 = m0 + w * 32;

  if (typ == 3) {
    float gw4[4];
#pragma unroll
    for (int ni = 0; ni < 4; ni++) gw4[ni] = g_norm_w[ni * 16 + tx];
#pragma unroll
    for (int mi = 0; mi < 2; mi++) {
#pragma unroll
      for (int reg = 0; reg < 4; reg++) {
        float s1 = acc[mi][0][reg] * acc[mi][0][reg] + acc[mi][1][reg] * acc[mi][1][reg]
                 + acc[mi][2][reg] * acc[mi][2][reg] + acc[mi][3][reg] * acc[mi][3][reg];
#pragma unroll
        for (int m = 1; m < 16; m <<= 1) s1 += __shfl_xor(s1, m, 64);
        float rms = rsqrtf(s1 * (1.f / 64.f) + 1e-6f);
        int rl = mi * 16 + quad * 4 + reg;
        float s2 = 0.f;
#pragma unroll
        for (int ni = 0; ni < 4; ni++) {
          float v = acc[mi][ni][reg] * rms * gw4[ni];
          unsigned short us = f2bf(v);
          Lw[rl * 72 + ni * 16 + tx] = us;
          float vb = bf2f(us);
          s2 += vb * vb;
        }
#pragma unroll
        for (int m = 1; m < 16; m <<= 1) s2 += __shfl_xor(s2, m, 64);
        if (tx == 0) g2[h * 1024 + mrow0 + rl] = s2;
      }
    }
#pragma unroll
    for (int rep = 0; rep < 4; rep++) {
      int idx = rep * 64 + lane;
      int r = idx >> 3, cc = (idx & 7) * 8;
      *(u16x8*)&gh[(size_t)(h * 1024 + mrow0 + r) * 64 + cc] = *(const u16x8*)&Lw[r * 72 + cc];
    }
  } else {
    float sc = (typ == 0) ? consts[h * 24] * 1.44269504089f : 1.0f;
#pragma unroll
    for (int mi = 0; mi < 2; mi++)
#pragma unroll
      for (int ni = 0; ni < 4; ni++)
#pragma unroll
        for (int reg = 0; reg < 4; reg++) {
          int rl = mi * 16 + quad * 4 + reg;
          Lw[rl * 72 + ni * 16 + tx] = f2bf(acc[mi][ni][reg] * sc);
        }
    unsigned short* dst = (typ == 0) ? qh : ((typ == 1) ? kh : vh);
#pragma unroll
    for (int rep = 0; rep < 4; rep++) {
      int idx = rep * 64 + lane;
      int r = idx >> 3, cc = (idx & 7) * 8;
      *(u16x8*)&dst[(size_t)(h * 1024 + mrow0 + r) * 64 + cc] = *(const u16x8*)&Lw[r * 72 + cc];
    }
    if (typ == 2) {
#pragma unroll
      for (int rep = 0; rep < 4; rep++) {
        int idx = rep * 64 + lane;
        int d = idx >> 2, rc = (idx & 3) * 8;
        u16x8 u;
#pragma unroll
        for (int j = 0; j < 8; j++) u[j] = Lw[(rc + j) * 72 + d];
        *(u16x8*)&vhT[(size_t)(h * 64 + d) * 1024 + mrow0 + rc] = u;
      }
    }
  }
}

// LDS-free out-proj GEMM: C[M][N] fp32 = swzA @ swzB^T, tile 128x64, grid (12,8).
__global__ __launch_bounds__(256) void gemm_frag_out(
    const unsigned short* __restrict__ swzA, const unsigned short* __restrict__ swzB,
    float* __restrict__ Cm) {
  int t = threadIdx.x, lane = t & 63, w = t >> 6;
  int quad = lane >> 4, tx = lane & 15;
  int n0 = blockIdx.x * 64;
  int m0 = blockIdx.y * 128;
  int nt0 = blockIdx.x * 4;
  int mt0 = blockIdx.y * 8 + w * 2;

  f32x4 acc[2][4] = {};
#pragma unroll 2
  for (int kb = 0; kb < 24; kb++) {
    bf16x8 a0 = *(const bf16x8*)&swzA[((size_t)((mt0 + 0) * 24 + kb) * 64 + lane) * 8];
    bf16x8 a1 = *(const bf16x8*)&swzA[((size_t)((mt0 + 1) * 24 + kb) * 64 + lane) * 8];
#pragma unroll
    for (int ni = 0; ni < 4; ni++) {
      bf16x8 b = *(const bf16x8*)&swzB[((size_t)((nt0 + ni) * 24 + kb) * 64 + lane) * 8];
      acc[0][ni] = __builtin_amdgcn_mfma_f32_16x16x32_bf16(a0, b, acc[0][ni], 0, 0, 0);
      acc[1][ni] = __builtin_amdgcn_mfma_f32_16x16x32_bf16(a1, b, acc[1][ni], 0, 0, 0);
    }
  }
#pragma unroll
  for (int mi = 0; mi < 2; mi++)
#pragma unroll
    for (int ni = 0; ni < 4; ni++)
#pragma unroll
      for (int reg = 0; reg < 4; reg++) {
        int row = m0 + w * 32 + mi * 16 + quad * 4 + reg;
        Cm[(size_t)row * CD + n0 + ni * 16 + tx] = acc[mi][ni][reg];
      }
}

// MFMA flash (unchanged from R8): 3 barriers/j-tile, sliced partials, no atomics.
__global__ __launch_bounds__(256, 3) void flash_kernel(
    const unsigned short* __restrict__ qh, const unsigned short* __restrict__ kh,
    const unsigned short* __restrict__ gh, const unsigned short* __restrict__ vhT,
    const float* __restrict__ g2, const float* __restrict__ consts,
    float* __restrict__ Opart, float* __restrict__ lsp, float* __restrict__ pdp) {
  int h = blockIdx.y;
  int uu = 143 - (int)blockIdx.x;  // heavy first
  int it = 0, rem = uu;
  for (it = 0; it < 32; ++it) {
    int njt_ = (it >> 1) + 1;
    int nc = (njt_ + 1) >> 1;
    if (rem < nc) break;
    rem -= nc;
  }
  int njt = (it >> 1) + 1;
  int jt0 = rem * 2;
  int jt1 = (jt0 + 2 < njt) ? (jt0 + 2) : njt;
  bool owns_diag = (jt1 == njt);
  int i0 = it * 32;
  int t = threadIdx.x;
  int lane = t & 63, w = t >> 6;
  int quad = lane >> 4, tx = lane & 15;
  int mi = w >> 1, nb = (w & 1) * 2;

  __shared__ __align__(16) unsigned short Qa[32 * 72];
  __shared__ __align__(16) unsigned short Ga[32 * 72];
  __shared__ __align__(16) unsigned short Ks[64 * 72];
  __shared__ __align__(16) unsigned short Gjs[64 * 72];
  __shared__ __align__(16) unsigned short Vt[64 * 72];
  __shared__ __align__(16) unsigned short psh[32 * 72];
  __shared__ float g2i[32], g2j[64], pdiag[32], lsum[32];

  const float* ch = consts + h * 24;
  float lkc = ch[1], bh2 = ch[2];
  int ntt = (int)ch[20];
  float i4t0 = ch[4];
  float inv4tau[8], logw[8];
#pragma unroll
  for (int tt = 0; tt < 8; tt++) { inv4tau[tt] = ch[4 + tt]; logw[tt] = ch[12 + tt]; }

  {
    int r = t >> 3, c8 = (t & 7) * 8;
    *(u16x8*)&Qa[r * 72 + c8] = *(const u16x8*)&qh[(size_t)(h * 1024 + i0 + r) * 64 + c8];
    *(u16x8*)&Ga[r * 72 + c8] = *(const u16x8*)&gh[(size_t)(h * 1024 + i0 + r) * 64 + c8];
  }
  if (t < 32) { g2i[t] = g2[h * 1024 + i0 + t]; pdiag[t] = 0.f; }
  __syncthreads();

  bf16x8 aq[2], ag[2];
#pragma unroll
  for (int ks = 0; ks < 2; ks++) {
    aq[ks] = *(const bf16x8*)&Qa[(mi * 16 + tx) * 72 + ks * 32 + quad * 8];
    ag[ks] = *(const bf16x8*)&Ga[(mi * 16 + tx) * 72 + ks * 32 + quad * 8];
  }

  f32x4 Oc[2] = {};
  float rowacc[4] = {0.f, 0.f, 0.f, 0.f};
  int r4 = t >> 2, cb = (t & 3) * 16;

  for (int jt = jt0; jt < jt1; jt++) {
    int j0 = jt * 64;
    __syncthreads();
    {
      const unsigned short* kp = &kh[(size_t)(h * 1024 + j0 + r4) * 64 + cb];
      const unsigned short* gp = &gh[(size_t)(h * 1024 + j0 + r4) * 64 + cb];
      const unsigned short* vp = &vhT[(size_t)(h * 64 + r4) * 1024 + j0 + cb];
      *(u16x8*)&Ks[r4 * 72 + cb] = *(const u16x8*)kp;
      *(u16x8*)&Ks[r4 * 72 + cb + 8] = *(const u16x8*)(kp + 8);
      *(u16x8*)&Gjs[r4 * 72 + cb] = *(const u16x8*)gp;
      *(u16x8*)&Gjs[r4 * 72 + cb + 8] = *(const u16x8*)(gp + 8);
      *(u16x8*)&Vt[r4 * 72 + cb] = *(const u16x8*)vp;
      *(u16x8*)&Vt[r4 * 72 + cb + 8] = *(const u16x8*)(vp + 8);
    }
    if (t < 64) g2j[t] = g2[h * 1024 + j0 + t];
    __syncthreads();

    f32x4 sqk[2] = {}, sgg[2] = {};
#pragma unroll
    for (int ni2 = 0; ni2 < 2; ni2++) {
#pragma unroll
      for (int ks = 0; ks < 2; ks++) {
        bf16x8 bk = *(const bf16x8*)&Ks[((nb + ni2) * 16 + tx) * 72 + ks * 32 + quad * 8];
        sqk[ni2] = __builtin_amdgcn_mfma_f32_16x16x32_bf16(aq[ks], bk, sqk[ni2], 0, 0, 0);
        bf16x8 bg = *(const bf16x8*)&Gjs[((nb + ni2) * 16 + tx) * 72 + ks * 32 + quad * 8];
        sgg[ni2] = __builtin_amdgcn_mfma_f32_16x16x32_bf16(ag[ks], bg, sgg[ni2], 0, 0, 0);
      }
    }

    float rs[4] = {0.f, 0.f, 0.f, 0.f};
#pragma unroll
    for (int ni2 = 0; ni2 < 2; ni2++) {
      int colg = j0 + (nb + ni2) * 16 + tx;
      float g2jv = g2j[(nb + ni2) * 16 + tx];
#pragma unroll
      for (int reg = 0; reg < 4; reg++) {
        int rowl = mi * 16 + quad * 4 + reg;
        int gi = i0 + rowl;
        float s = fmaxf(g2i[rowl] + g2jv - 2.0f * sgg[ni2][reg], 0.0f);
        float lse2;
        if (ntt == 1) {
          lse2 = -bh2 * __builtin_amdgcn_logf(fmaf(s, i4t0, 1.0f));
        } else {
          float se = 0.f;
#pragma unroll
          for (int tt = 0; tt < 8; tt++) {
            float lv = __builtin_amdgcn_logf(fmaf(s, inv4tau[tt], 1.0f));
            se += __builtin_amdgcn_exp2f(fmaf(-bh2, lv, logw[tt]));
          }
          lse2 = __builtin_amdgcn_logf(se + 1e-30f);
        }
        float b = fmaf(lkc, lse2, sqk[ni2][reg]);  // q pre-scaled by dpc2
        float p = (colg <= gi) ? __builtin_amdgcn_exp2f(b) : 0.0f;
        rs[reg] += p;
        psh[rowl * 72 + (nb + ni2) * 16 + tx] = f2bf(p);
        if (colg == gi) pdiag[rowl] = p;
      }
    }
#pragma unroll
    for (int reg = 0; reg < 4; reg++) {
#pragma unroll
      for (int m = 1; m < 16; m <<= 1) rs[reg] += __shfl_xor(rs[reg], m, 64);
      rowacc[reg] += rs[reg];
    }
    __syncthreads();

    bf16x8 ap[2];
#pragma unroll
    for (int ks = 0; ks < 2; ks++)
      ap[ks] = *(const bf16x8*)&psh[(mi * 16 + tx) * 72 + ks * 32 + quad * 8];
#pragma unroll
    for (int nd2 = 0; nd2 < 2; nd2++) {
#pragma unroll
      for (int ks = 0; ks < 2; ks++) {
        bf16x8 bv = *(const bf16x8*)&Vt[((nb + nd2) * 16 + tx) * 72 + ks * 32 + quad * 8];
        Oc[nd2] = __builtin_amdgcn_mfma_f32_16x16x32_bf16(ap[ks], bv, Oc[nd2], 0, 0, 0);
      }
    }
  }

  if ((w & 1) == 0 && tx == 0) {
#pragma unroll
    for (int reg = 0; reg < 4; reg++) lsum[mi * 16 + quad * 4 + reg] = rowacc[reg];
  }
  __syncthreads();
  if ((w & 1) == 1 && tx == 0) {
#pragma unroll
    for (int reg = 0; reg < 4; reg++) {
      int rowl = mi * 16 + quad * 4 + reg;
      lsp[(size_t)(rem * HN + h) * 1024 + i0 + rowl] = lsum[rowl] + rowacc[reg];
    }
  }
  float* Ob = Opart + (size_t)((rem * HN + h) * 1024 + i0) * 64;
#pragma unroll
  for (int nd2 = 0; nd2 < 2; nd2++) {
#pragma unroll
    for (int reg = 0; reg < 4; reg++) {
      int rowl = mi * 16 + quad * 4 + reg;
      Ob[rowl * 64 + (nb + nd2) * 16 + tx] = Oc[nd2][reg];
    }
  }
  if (owns_diag && t < 32) pdp[h * 1024 + i0 + t] = pdiag[t];
}

// Sum chunk slices; y = osc*(c1*(P@v) + c2*v); write yb in MFMA-frag swizzle.
__global__ __launch_bounds__(256) void finalize_kernel(
    const float* __restrict__ Opart, const float* __restrict__ lsp,
    const float* __restrict__ pdp, const unsigned short* __restrict__ vh,
    const float* __restrict__ consts, unsigned short* __restrict__ yb) {
  int h = blockIdx.y;
  int t = threadIdx.x;
  int rl = t >> 4, d4 = t & 15;
  int gi = blockIdx.x * 16 + rl;
  int it = gi >> 5;
  int nc = (((it >> 1) + 1) + 1) >> 1;
  float alpha = consts[288];
  float osc = consts[h * 24 + 3];
  float4 Ov = make_float4(0.f, 0.f, 0.f, 0.f);
  float l = 0.f;
  for (int c = 0; c < nc; c++) {
    float4 p = *(const float4*)&Opart[(size_t)((c * HN + h) * 1024 + gi) * 64 + 4 * d4];
    Ov.x += p.x; Ov.y += p.y; Ov.z += p.z; Ov.w += p.w;
    l += lsp[(size_t)(c * HN + h) * 1024 + gi];
  }
  l = fmaxf(l, 1e-12f);
  float Pii = pdp[h * TSEQ + gi] / l;
  float inv1p = 1.0f / (1.0f + Pii);
  float c1 = (1.0f - alpha) + alpha * inv1p;
  float c2 = alpha * Pii * inv1p;
  float invl = 1.0f / l;
  u16x4 vb = *(const u16x4*)&vh[(size_t)(h * 1024 + gi) * 64 + 4 * d4];
  u16x4 o;
  o[0] = f2bf(osc * (c1 * Ov.x * invl + c2 * bf2f(vb[0])));
  o[1] = f2bf(osc * (c1 * Ov.y * invl + c2 * bf2f(vb[1])));
  o[2] = f2bf(osc * (c1 * Ov.z * invl + c2 * bf2f(vb[2])));
  o[3] = f2bf(osc * (c1 * Ov.w * invl + c2 * bf2f(vb[3])));
  // swizzled store: k = h*64 + 4*d4
  int k = h * 64 + 4 * d4;
  int kb = k >> 5, q8 = (k & 31) >> 3, j0 = k & 7;
  int mt = gi >> 4, txl = gi & 15;
  size_t off = (((size_t)mt * 24 + kb) * 64 + q8 * 16 + txl) * 8 + j0;
  *(u16x4*)&yb[off] = o;
}

extern "C" void kernel_launch(void* const* d_in, const int* in_sizes, int n_in,
                              void* d_out, int out_size, void* d_ws, size_t ws_size,
                              hipStream_t stream) {
  (void)in_sizes; (void)n_in; (void)out_size; (void)ws_size;
  const float* x          = (const float*)d_in[0];
  const float* W_qkvg     = (const float*)d_in[1];
  const float* W_out      = (const float*)d_in[2];
  const float* lam        = (const float*)d_in[3];
  const float* log_tau    = (const float*)d_in[4];
  const float* logit_w    = (const float*)d_in[5];
  const float* beta       = (const float*)d_in[6];
  const float* out_scale  = (const float*)d_in[7];
  const float* dp_scale   = (const float*)d_in[8];
  const float* logk_scale = (const float*)d_in[9];
  const float* dt_logit   = (const float*)d_in[10];
  const float* g_norm_w   = (const float*)d_in[11];
  float* ws = (float*)d_ws;
  unsigned short* qh  = (unsigned short*)(ws + OFF_QH);
  unsigned short* kh  = (unsigned short*)(ws + OFF_KH);
  unsigned short* gh  = (unsigned short*)(ws + OFF_GH);
  unsigned short* vhT = (unsigned short*)(ws + OFF_VHT);
  unsigned short* vh  = (unsigned short*)(ws + OFF_VH);
  float* g2     = ws + OFF_G2;
  unsigned short* yb  = (unsigned short*)(ws + OFF_YB);
  float* consts = ws + OFF_CONSTS;
  float* Opart  = ws + OFF_OPART;
  float* lsp    = ws + OFF_LS;
  float* pdp    = ws + OFF_PD;
  unsigned short* swzA = (unsigned short*)(ws + OFF_XB);
  unsigned short* swzWQ = (unsigned short*)(ws + OFF_WQB);
  unsigned short* swzWO = (unsigned short*)(ws + OFF_WOB);
  float* out = (float*)d_out;

  prep_kernel<<<dim3(1), dim3(64), 0, stream>>>(lam, log_tau, logit_w, beta,
                                                out_scale, dp_scale, logk_scale,
                                                dt_logit, consts);
  convert_kernel<<<dim3((NG_X + NG_WQ + NG_WO) / 256), dim3(256), 0, stream>>>(
      x, W_qkvg, W_out, swzA, swzWQ, swzWO);
  gemm_frag_qkvg<<<dim3(48, 8), dim3(256), 0, stream>>>(swzA, swzWQ, consts, g_norm_w,
                                                        qh, kh, gh, vh, vhT, g2);
  flash_kernel<<<dim3(144, 12), dim3(256), 0, stream>>>(qh, kh, gh, vhT, g2, consts,
                                                        Opart, lsp, pdp);
  finalize_kernel<<<dim3(64, 12), dim3(256), 0, stream>>>(Opart, lsp, pdp, vh, consts, yb);
  gemm_frag_out<<<dim3(12, 8), dim3(256), 0, stream>>>(yb, swzWO, out);
}

// Round 10
// 149.614 us; speedup vs baseline: 1.0910x; 1.0439x over previous
//
#include <hip/hip_runtime.h>
#include <math.h>

#define TSEQ 1024
#define CD   768
#define HN   12
#define DD   64
#define CH   4   // j-tiles per flash chunk

// workspace float offsets (~30 MB)
#define OFF_QH     0          // bf16 12*1024*64 -> 393216 floats each
#define OFF_KH     393216
#define OFF_GH     786432
#define OFF_VHT    1179648    // bf16 d-major [H][D][T]
#define OFF_VH     1572864    // bf16 row-major [H][T][D]
#define OFF_G2     1966080    // 12*1024
#define OFF_YB     1978368    // bf16 1024*768 (MFMA-frag swizzled)
#define OFF_CONSTS 2371584    // 512
#define OFF_OPART  2372096    // 4 slices * 786432 = 3145728
#define OFF_LS     5517824    // 4 slices * 12288
#define OFF_PD     5566976    // 12288
#define OFF_XB     5579264    // bf16 1024*768 swizzled
#define OFF_WQB    5972480    // bf16 3072*768 swizzled
#define OFF_WOB    7152128    // bf16 768*768 swizzled (end 7447040)

#define NG_X  98304           // 1024/16 * 24 * 64
#define NG_WQ 294912
#define NG_WO 73728

typedef __bf16 bf16x8 __attribute__((ext_vector_type(8)));
typedef float  f32x4  __attribute__((ext_vector_type(4)));
typedef unsigned short u16x8 __attribute__((ext_vector_type(8)));
typedef unsigned short u16x4 __attribute__((ext_vector_type(4)));

__device__ inline unsigned short f2bf(float f) {
  unsigned int u = __float_as_uint(f);
  return (unsigned short)((u + 0x7fffu + ((u >> 16) & 1u)) >> 16);  // RNE
}
__device__ inline float bf2f(unsigned short u) {
  return __uint_as_float((unsigned)u << 16);
}

// consts per head (stride 24): [0]=lam*dp_scale/6.4, [1]=(1-lam)*logk_scale,
// [2]=clip(beta)/2, [3]=out_scale, [4..11]=1/(4*tau), [12..19]=log2(w+1e-12),
// [20]=ntt. alpha at [288].

// fp32 -> bf16 convert + MFMA-fragment swizzle; block 0 also runs prep.
__global__ __launch_bounds__(256) void convert_kernel(
    const float* __restrict__ x, const float* __restrict__ wq,
    const float* __restrict__ wo, unsigned short* __restrict__ swzA,
    unsigned short* __restrict__ swzWQ, unsigned short* __restrict__ swzWO,
    const float* __restrict__ lam_p, const float* __restrict__ log_tau,
    const float* __restrict__ logit_w, const float* __restrict__ beta,
    const float* __restrict__ out_scale, const float* __restrict__ dp_scale,
    const float* __restrict__ logk_scale, const float* __restrict__ dt_logit,
    float* __restrict__ consts) {
  if (blockIdx.x == 0 && threadIdx.x < 64) {
    int h = threadIdx.x;
    if (h == 0) {
      float dt = 1.0f / (1.0f + __expf(-dt_logit[0]));
      consts[288] = 0.1f * dt;  // ESR_ALPHA * dt
    }
    if (h < HN) {
      float lam = lam_p[0];
      float* c = consts + h * 24;
      c[0] = lam * dp_scale[h] * (1.0f / 6.4f);
      c[1] = (1.0f - lam) * logk_scale[h];
      float b = fminf(fmaxf(beta[h], 0.5f), 2.5f);
      c[2] = 0.5f * b;
      c[3] = out_scale[h];
      float m = -1e30f;
      float lw[8];
      bool uni = true;
      for (int t = 0; t < 8; t++) {
        lw[t] = logit_w[h * 8 + t];
        m = fmaxf(m, lw[t]);
        if (log_tau[h * 8 + t] != log_tau[h * 8] || lw[t] != lw[0]) uni = false;
      }
      float s = 0.f;
      float e[8];
      for (int t = 0; t < 8; t++) { e[t] = __expf(lw[t] - m); s += e[t]; }
      for (int t = 0; t < 8; t++) {
        float w = e[t] / s;
        c[12 + t] = log2f(w + 1e-12f);
        float tau = fmaxf(__expf(log_tau[h * 8 + t]), 1e-6f);
        c[4 + t] = 1.0f / (4.0f * tau);
      }
      c[20] = uni ? 1.0f : 8.0f;
    }
  }
  int g = blockIdx.x * 256 + threadIdx.x;
  const float* src;
  unsigned short* dst;
  int lg;
  if (g < NG_X) { src = x; dst = swzA; lg = g; }
  else if (g < NG_X + NG_WQ) { src = wq; dst = swzWQ; lg = g - NG_X; }
  else if (g < NG_X + NG_WQ + NG_WO) { src = wo; dst = swzWO; lg = g - NG_X - NG_WQ; }
  else return;
  int lane = lg & 63;
  int kb = (lg >> 6) % 24;
  int t16 = lg / (64 * 24);
  int row = t16 * 16 + (lane & 15);
  int col = kb * 32 + (lane >> 4) * 8;
  const float* s = &src[(size_t)row * 768 + col];
  float4 a = *(const float4*)s;
  float4 b = *(const float4*)(s + 4);
  u16x8 u;
  u[0] = f2bf(a.x); u[1] = f2bf(a.y); u[2] = f2bf(a.z); u[3] = f2bf(a.w);
  u[4] = f2bf(b.x); u[5] = f2bf(b.y); u[6] = f2bf(b.z); u[7] = f2bf(b.w);
  *(u16x8*)&dst[(size_t)lg * 8] = u;
}

// LDS-free qkvg GEMM on swizzled fragments + fused per-wave head-split epilogue.
__global__ __launch_bounds__(256) void gemm_frag_qkvg(
    const unsigned short* __restrict__ swzA, const unsigned short* __restrict__ swzB,
    const float* __restrict__ consts, const float* __restrict__ g_norm_w,
    unsigned short* __restrict__ qh, unsigned short* __restrict__ kh,
    unsigned short* __restrict__ gh, unsigned short* __restrict__ vh,
    unsigned short* __restrict__ vhT, float* __restrict__ g2) {
  __shared__ __align__(16) unsigned short Ls[128 * 72];
  int t = threadIdx.x, lane = t & 63, w = t >> 6;
  int quad = lane >> 4, tx = lane & 15;
  int ntile = blockIdx.x;
  int m0 = blockIdx.y * 128;
  int nt0 = ntile * 4;
  int mt0 = blockIdx.y * 8 + w * 2;

  f32x4 acc[2][4] = {};
#pragma unroll 2
  for (int kb = 0; kb < 24; kb++) {
    bf16x8 a0 = *(const bf16x8*)&swzA[((size_t)((mt0 + 0) * 24 + kb) * 64 + lane) * 8];
    bf16x8 a1 = *(const bf16x8*)&swzA[((size_t)((mt0 + 1) * 24 + kb) * 64 + lane) * 8];
#pragma unroll
    for (int ni = 0; ni < 4; ni++) {
      bf16x8 b = *(const bf16x8*)&swzB[((size_t)((nt0 + ni) * 24 + kb) * 64 + lane) * 8];
      acc[0][ni] = __builtin_amdgcn_mfma_f32_16x16x32_bf16(a0, b, acc[0][ni], 0, 0, 0);
      acc[1][ni] = __builtin_amdgcn_mfma_f32_16x16x32_bf16(a1, b, acc[1][ni], 0, 0, 0);
    }
  }

  int typ = ntile / 12;
  int h = ntile % 12;
  unsigned short* Lw = Ls + w * (32 * 72);
  int mrow0 = m0 + w * 32;

  if (typ == 3) {
    float gw4[4];
#pragma unroll
    for (int ni = 0; ni < 4; ni++) gw4[ni] = g_norm_w[ni * 16 + tx];
#pragma unroll
    for (int mi = 0; mi < 2; mi++) {
#pragma unroll
      for (int reg = 0; reg < 4; reg++) {
        float s1 = acc[mi][0][reg] * acc[mi][0][reg] + acc[mi][1][reg] * acc[mi][1][reg]
                 + acc[mi][2][reg] * acc[mi][2][reg] + acc[mi][3][reg] * acc[mi][3][reg];
#pragma unroll
        for (int m = 1; m < 16; m <<= 1) s1 += __shfl_xor(s1, m, 64);
        float rms = rsqrtf(s1 * (1.f / 64.f) + 1e-6f);
        int rl = mi * 16 + quad * 4 + reg;
        float s2 = 0.f;
#pragma unroll
        for (int ni = 0; ni < 4; ni++) {
          float v = acc[mi][ni][reg] * rms * gw4[ni];
          unsigned short us = f2bf(v);
          Lw[rl * 72 + ni * 16 + tx] = us;
          float vb = bf2f(us);
          s2 += vb * vb;
        }
#pragma unroll
        for (int m = 1; m < 16; m <<= 1) s2 += __shfl_xor(s2, m, 64);
        if (tx == 0) g2[h * 1024 + mrow0 + rl] = s2;
      }
    }
#pragma unroll
    for (int rep = 0; rep < 4; rep++) {
      int idx = rep * 64 + lane;
      int r = idx >> 3, cc = (idx & 7) * 8;
      *(u16x8*)&gh[(size_t)(h * 1024 + mrow0 + r) * 64 + cc] = *(const u16x8*)&Lw[r * 72 + cc];
    }
  } else {
    float sc = (typ == 0) ? consts[h * 24] * 1.44269504089f : 1.0f;
#pragma unroll
    for (int mi = 0; mi < 2; mi++)
#pragma unroll
      for (int ni = 0; ni < 4; ni++)
#pragma unroll
        for (int reg = 0; reg < 4; reg++) {
          int rl = mi * 16 + quad * 4 + reg;
          Lw[rl * 72 + ni * 16 + tx] = f2bf(acc[mi][ni][reg] * sc);
        }
    unsigned short* dst = (typ == 0) ? qh : ((typ == 1) ? kh : vh);
#pragma unroll
    for (int rep = 0; rep < 4; rep++) {
      int idx = rep * 64 + lane;
      int r = idx >> 3, cc = (idx & 7) * 8;
      *(u16x8*)&dst[(size_t)(h * 1024 + mrow0 + r) * 64 + cc] = *(const u16x8*)&Lw[r * 72 + cc];
    }
    if (typ == 2) {
#pragma unroll
      for (int rep = 0; rep < 4; rep++) {
        int idx = rep * 64 + lane;
        int d = idx >> 2, rc = (idx & 3) * 8;
        u16x8 u;
#pragma unroll
        for (int j = 0; j < 8; j++) u[j] = Lw[(rc + j) * 72 + d];
        *(u16x8*)&vhT[(size_t)(h * 64 + d) * 1024 + mrow0 + rc] = u;
      }
    }
  }
}

// LDS-free out-proj GEMM.
__global__ __launch_bounds__(256) void gemm_frag_out(
    const unsigned short* __restrict__ swzA, const unsigned short* __restrict__ swzB,
    float* __restrict__ Cm) {
  int t = threadIdx.x, lane = t & 63, w = t >> 6;
  int quad = lane >> 4, tx = lane & 15;
  int n0 = blockIdx.x * 64;
  int m0 = blockIdx.y * 128;
  int nt0 = blockIdx.x * 4;
  int mt0 = blockIdx.y * 8 + w * 2;

  f32x4 acc[2][4] = {};
#pragma unroll 2
  for (int kb = 0; kb < 24; kb++) {
    bf16x8 a0 = *(const bf16x8*)&swzA[((size_t)((mt0 + 0) * 24 + kb) * 64 + lane) * 8];
    bf16x8 a1 = *(const bf16x8*)&swzA[((size_t)((mt0 + 1) * 24 + kb) * 64 + lane) * 8];
#pragma unroll
    for (int ni = 0; ni < 4; ni++) {
      bf16x8 b = *(const bf16x8*)&swzB[((size_t)((nt0 + ni) * 24 + kb) * 64 + lane) * 8];
      acc[0][ni] = __builtin_amdgcn_mfma_f32_16x16x32_bf16(a0, b, acc[0][ni], 0, 0, 0);
      acc[1][ni] = __builtin_amdgcn_mfma_f32_16x16x32_bf16(a1, b, acc[1][ni], 0, 0, 0);
    }
  }
#pragma unroll
  for (int mi = 0; mi < 2; mi++)
#pragma unroll
    for (int ni = 0; ni < 4; ni++)
#pragma unroll
      for (int reg = 0; reg < 4; reg++) {
        int row = m0 + w * 32 + mi * 16 + quad * 4 + reg;
        Cm[(size_t)row * CD + n0 + ni * 16 + tx] = acc[mi][ni][reg];
      }
}

// MFMA flash v3: chunks of <=4 j-tiles, register prefetch double-buffer,
// 32 KB LDS (Q/G staged through Ks/Gjs), occupancy 4.
__global__ __launch_bounds__(256, 4) void flash_kernel(
    const unsigned short* __restrict__ qh, const unsigned short* __restrict__ kh,
    const unsigned short* __restrict__ gh, const unsigned short* __restrict__ vhT,
    const float* __restrict__ g2, const float* __restrict__ consts,
    float* __restrict__ Opart, float* __restrict__ lsp, float* __restrict__ pdp) {
  int h = blockIdx.y;
  int uu = 79 - (int)blockIdx.x;  // heavy first
  int it = 0, rem = uu;
  for (it = 0; it < 32; ++it) {
    int njt_ = (it >> 1) + 1;
    int nc = (njt_ + CH - 1) / CH;
    if (rem < nc) break;
    rem -= nc;
  }
  int njt = (it >> 1) + 1;
  int jt0 = rem * CH;
  int jt1 = (jt0 + CH < njt) ? (jt0 + CH) : njt;
  bool owns_diag = (jt1 == njt);
  int i0 = it * 32;
  int t = threadIdx.x;
  int lane = t & 63, w = t >> 6;
  int quad = lane >> 4, tx = lane & 15;
  int mi = w >> 1, nb = (w & 1) * 2;

  __shared__ __align__(16) unsigned short Ks[64 * 72];
  __shared__ __align__(16) unsigned short Gjs[64 * 72];
  __shared__ __align__(16) unsigned short Vt[64 * 72];
  __shared__ __align__(16) unsigned short psh[32 * 72];
  __shared__ float g2i[32], g2j[64], pdiag[32], lsum[32];

  const float* ch = consts + h * 24;
  float lkc = ch[1], bh2 = ch[2];
  int ntt = (int)ch[20];
  float i4t0 = ch[4];
  float inv4tau[8], logw[8];
#pragma unroll
  for (int tt = 0; tt < 8; tt++) { inv4tau[tt] = ch[4 + tt]; logw[tt] = ch[12 + tt]; }

  // stage Q (into Ks) and G (into Gjs) for the i-tile, extract frags to regs
  {
    int r = t >> 3, c8 = (t & 7) * 8;
    *(u16x8*)&Ks[r * 72 + c8] = *(const u16x8*)&qh[(size_t)(h * 1024 + i0 + r) * 64 + c8];
    *(u16x8*)&Gjs[r * 72 + c8] = *(const u16x8*)&gh[(size_t)(h * 1024 + i0 + r) * 64 + c8];
  }
  if (t < 32) { g2i[t] = g2[h * 1024 + i0 + t]; pdiag[t] = 0.f; }
  __syncthreads();

  bf16x8 aq[2], ag[2];
#pragma unroll
  for (int ks = 0; ks < 2; ks++) {
    aq[ks] = *(const bf16x8*)&Ks[(mi * 16 + tx) * 72 + ks * 32 + quad * 8];
    ag[ks] = *(const bf16x8*)&Gjs[(mi * 16 + tx) * 72 + ks * 32 + quad * 8];
  }

  f32x4 Oc[2] = {};
  float rowacc[4] = {0.f, 0.f, 0.f, 0.f};
  int r4 = t >> 2, cb = (t & 3) * 16;

  // prefetch first j-tile into registers
  u16x8 pk0, pk1, pg0, pg1, pv0, pv1;
  float pg2 = 0.f;
  {
    int j0 = jt0 * 64;
    const unsigned short* kp = &kh[(size_t)(h * 1024 + j0 + r4) * 64 + cb];
    const unsigned short* gp = &gh[(size_t)(h * 1024 + j0 + r4) * 64 + cb];
    const unsigned short* vp = &vhT[(size_t)(h * 64 + r4) * 1024 + j0 + cb];
    pk0 = *(const u16x8*)kp; pk1 = *(const u16x8*)(kp + 8);
    pg0 = *(const u16x8*)gp; pg1 = *(const u16x8*)(gp + 8);
    pv0 = *(const u16x8*)vp; pv1 = *(const u16x8*)(vp + 8);
    if (t < 64) pg2 = g2[h * 1024 + j0 + t];
  }

  for (int jt = jt0; jt < jt1; jt++) {
    int j0 = jt * 64;
    __syncthreads();  // A: prior tile reads (and initial frag reads) done
    *(u16x8*)&Ks[r4 * 72 + cb] = pk0;
    *(u16x8*)&Ks[r4 * 72 + cb + 8] = pk1;
    *(u16x8*)&Gjs[r4 * 72 + cb] = pg0;
    *(u16x8*)&Gjs[r4 * 72 + cb + 8] = pg1;
    *(u16x8*)&Vt[r4 * 72 + cb] = pv0;
    *(u16x8*)&Vt[r4 * 72 + cb + 8] = pv1;
    if (t < 64) g2j[t] = pg2;
    __syncthreads();  // B: staging visible

    // issue next tile's prefetch (latency hides under this tile's compute)
    if (jt + 1 < jt1) {
      int jn = j0 + 64;
      const unsigned short* kp = &kh[(size_t)(h * 1024 + jn + r4) * 64 + cb];
      const unsigned short* gp = &gh[(size_t)(h * 1024 + jn + r4) * 64 + cb];
      const unsigned short* vp = &vhT[(size_t)(h * 64 + r4) * 1024 + jn + cb];
      pk0 = *(const u16x8*)kp; pk1 = *(const u16x8*)(kp + 8);
      pg0 = *(const u16x8*)gp; pg1 = *(const u16x8*)(gp + 8);
      pv0 = *(const u16x8*)vp; pv1 = *(const u16x8*)(vp + 8);
      if (t < 64) pg2 = g2[h * 1024 + jn + t];
    }

    f32x4 sqk[2] = {}, sgg[2] = {};
#pragma unroll
    for (int ni2 = 0; ni2 < 2; ni2++) {
#pragma unroll
      for (int ks = 0; ks < 2; ks++) {
        bf16x8 bk = *(const bf16x8*)&Ks[((nb + ni2) * 16 + tx) * 72 + ks * 32 + quad * 8];
        sqk[ni2] = __builtin_amdgcn_mfma_f32_16x16x32_bf16(aq[ks], bk, sqk[ni2], 0, 0, 0);
        bf16x8 bg = *(const bf16x8*)&Gjs[((nb + ni2) * 16 + tx) * 72 + ks * 32 + quad * 8];
        sgg[ni2] = __builtin_amdgcn_mfma_f32_16x16x32_bf16(ag[ks], bg, sgg[ni2], 0, 0, 0);
      }
    }

    float rs[4] = {0.f, 0.f, 0.f, 0.f};
#pragma unroll
    for (int ni2 = 0; ni2 < 2; ni2++) {
      int colg = j0 + (nb + ni2) * 16 + tx;
      float g2jv = g2j[(nb + ni2) * 16 + tx];
#pragma unroll
      for (int reg = 0; reg < 4; reg++) {
        int rowl = mi * 16 + quad * 4 + reg;
        int gi = i0 + rowl;
        float s = fmaxf(g2i[rowl] + g2jv - 2.0f * sgg[ni2][reg], 0.0f);
        float lse2;
        if (ntt == 1) {
          lse2 = -bh2 * __builtin_amdgcn_logf(fmaf(s, i4t0, 1.0f));
        } else {
          float se = 0.f;
#pragma unroll
          for (int tt = 0; tt < 8; tt++) {
            float lv = __builtin_amdgcn_logf(fmaf(s, inv4tau[tt], 1.0f));
            se += __builtin_amdgcn_exp2f(fmaf(-bh2, lv, logw[tt]));
          }
          lse2 = __builtin_amdgcn_logf(se + 1e-30f);
        }
        float b = fmaf(lkc, lse2, sqk[ni2][reg]);  // q pre-scaled by dpc2
        float p = (colg <= gi) ? __builtin_amdgcn_exp2f(b) : 0.0f;
        rs[reg] += p;
        psh[rowl * 72 + (nb + ni2) * 16 + tx] = f2bf(p);
        if (colg == gi) pdiag[rowl] = p;
      }
    }
#pragma unroll
    for (int reg = 0; reg < 4; reg++) {
#pragma unroll
      for (int m = 1; m < 16; m <<= 1) rs[reg] += __shfl_xor(rs[reg], m, 64);
      rowacc[reg] += rs[reg];
    }
    __syncthreads();  // C: psh visible

    bf16x8 ap[2];
#pragma unroll
    for (int ks = 0; ks < 2; ks++)
      ap[ks] = *(const bf16x8*)&psh[(mi * 16 + tx) * 72 + ks * 32 + quad * 8];
#pragma unroll
    for (int nd2 = 0; nd2 < 2; nd2++) {
#pragma unroll
      for (int ks = 0; ks < 2; ks++) {
        bf16x8 bv = *(const bf16x8*)&Vt[((nb + nd2) * 16 + tx) * 72 + ks * 32 + quad * 8];
        Oc[nd2] = __builtin_amdgcn_mfma_f32_16x16x32_bf16(ap[ks], bv, Oc[nd2], 0, 0, 0);
      }
    }
  }

  if ((w & 1) == 0 && tx == 0) {
#pragma unroll
    for (int reg = 0; reg < 4; reg++) lsum[mi * 16 + quad * 4 + reg] = rowacc[reg];
  }
  __syncthreads();
  if ((w & 1) == 1 && tx == 0) {
#pragma unroll
    for (int reg = 0; reg < 4; reg++) {
      int rowl = mi * 16 + quad * 4 + reg;
      lsp[(size_t)(rem * HN + h) * 1024 + i0 + rowl] = lsum[rowl] + rowacc[reg];
    }
  }
  float* Ob = Opart + (size_t)((rem * HN + h) * 1024 + i0) * 64;
#pragma unroll
  for (int nd2 = 0; nd2 < 2; nd2++) {
#pragma unroll
    for (int reg = 0; reg < 4; reg++) {
      int rowl = mi * 16 + quad * 4 + reg;
      Ob[rowl * 64 + (nb + nd2) * 16 + tx] = Oc[nd2][reg];
    }
  }
  if (owns_diag && t < 32) pdp[h * 1024 + i0 + t] = pdiag[t];
}

// Sum chunk slices (<=4); y = osc*(c1*(P@v) + c2*v); write yb MFMA-frag swizzled.
__global__ __launch_bounds__(256) void finalize_kernel(
    const float* __restrict__ Opart, const float* __restrict__ lsp,
    const float* __restrict__ pdp, const unsigned short* __restrict__ vh,
    const float* __restrict__ consts, unsigned short* __restrict__ yb) {
  int h = blockIdx.y;
  int t = threadIdx.x;
  int rl = t >> 4, d4 = t & 15;
  int gi = blockIdx.x * 16 + rl;
  int it = gi >> 5;
  int njt = (it >> 1) + 1;
  int nc = (njt + CH - 1) / CH;
  float alpha = consts[288];
  float osc = consts[h * 24 + 3];
  float4 Ov = make_float4(0.f, 0.f, 0.f, 0.f);
  float l = 0.f;
  for (int c = 0; c < nc; c++) {
    float4 p = *(const float4*)&Opart[(size_t)((c * HN + h) * 1024 + gi) * 64 + 4 * d4];
    Ov.x += p.x; Ov.y += p.y; Ov.z += p.z; Ov.w += p.w;
    l += lsp[(size_t)(c * HN + h) * 1024 + gi];
  }
  l = fmaxf(l, 1e-12f);
  float Pii = pdp[h * TSEQ + gi] / l;
  float inv1p = 1.0f / (1.0f + Pii);
  float c1 = (1.0f - alpha) + alpha * inv1p;
  float c2 = alpha * Pii * inv1p;
  float invl = 1.0f / l;
  u16x4 vb = *(const u16x4*)&vh[(size_t)(h * 1024 + gi) * 64 + 4 * d4];
  u16x4 o;
  o[0] = f2bf(osc * (c1 * Ov.x * invl + c2 * bf2f(vb[0])));
  o[1] = f2bf(osc * (c1 * Ov.y * invl + c2 * bf2f(vb[1])));
  o[2] = f2bf(osc * (c1 * Ov.z * invl + c2 * bf2f(vb[2])));
  o[3] = f2bf(osc * (c1 * Ov.w * invl + c2 * bf2f(vb[3])));
  int k = h * 64 + 4 * d4;
  int kb = k >> 5, q8 = (k & 31) >> 3, j0 = k & 7;
  int mt = gi >> 4, txl = gi & 15;
  size_t off = (((size_t)mt * 24 + kb) * 64 + q8 * 16 + txl) * 8 + j0;
  *(u16x4*)&yb[off] = o;
}

extern "C" void kernel_launch(void* const* d_in, const int* in_sizes, int n_in,
                              void* d_out, int out_size, void* d_ws, size_t ws_size,
                              hipStream_t stream) {
  (void)in_sizes; (void)n_in; (void)out_size; (void)ws_size;
  const float* x          = (const float*)d_in[0];
  const float* W_qkvg     = (const float*)d_in[1];
  const float* W_out      = (const float*)d_in[2];
  const float* lam        = (const float*)d_in[3];
  const float* log_tau    = (const float*)d_in[4];
  const float* logit_w    = (const float*)d_in[5];
  const float* beta       = (const float*)d_in[6];
  const float* out_scale  = (const float*)d_in[7];
  const float* dp_scale   = (const float*)d_in[8];
  const float* logk_scale = (const float*)d_in[9];
  const float* dt_logit   = (const float*)d_in[10];
  const float* g_norm_w   = (const float*)d_in[11];
  float* ws = (float*)d_ws;
  unsigned short* qh  = (unsigned short*)(ws + OFF_QH);
  unsigned short* kh  = (unsigned short*)(ws + OFF_KH);
  unsigned short* gh  = (unsigned short*)(ws + OFF_GH);
  unsigned short* vhT = (unsigned short*)(ws + OFF_VHT);
  unsigned short* vh  = (unsigned short*)(ws + OFF_VH);
  float* g2     = ws + OFF_G2;
  unsigned short* yb  = (unsigned short*)(ws + OFF_YB);
  float* consts = ws + OFF_CONSTS;
  float* Opart  = ws + OFF_OPART;
  float* lsp    = ws + OFF_LS;
  float* pdp    = ws + OFF_PD;
  unsigned short* swzA = (unsigned short*)(ws + OFF_XB);
  unsigned short* swzWQ = (unsigned short*)(ws + OFF_WQB);
  unsigned short* swzWO = (unsigned short*)(ws + OFF_WOB);
  float* out = (float*)d_out;

  convert_kernel<<<dim3((NG_X + NG_WQ + NG_WO) / 256), dim3(256), 0, stream>>>(
      x, W_qkvg, W_out, swzA, swzWQ, swzWO,
      lam, log_tau, logit_w, beta, out_scale, dp_scale, logk_scale, dt_logit, consts);
  gemm_frag_qkvg<<<dim3(48, 8), dim3(256), 0, stream>>>(swzA, swzWQ, consts, g_norm_w,
                                                        qh, kh, gh, vh, vhT, g2);
  flash_kernel<<<dim3(80, 12), dim3(256), 0, stream>>>(qh, kh, gh, vhT, g2, consts,
                                                       Opart, lsp, pdp);
  finalize_kernel<<<dim3(64, 12), dim3(256), 0, stream>>>(Opart, lsp, pdp, vh, consts, yb);
  gemm_frag_out<<<dim3(12, 8), dim3(256), 0, stream>>>(yb, swzWO, out);
}